// Round 2
// baseline (309.208 us; speedup 1.0000x reference)
//
#include <hip/hip_runtime.h>
#include <hip/hip_bf16.h>

typedef __attribute__((ext_vector_type(8))) __bf16 bf16x8;
typedef __attribute__((ext_vector_type(4))) float f32x4;

#define HBF __hip_bfloat16

// B=2, N=2048, C=768, H=12, D=64
static constexpr float SCALE_C = 0.125f;   // D^-0.5
static constexpr float STEP_C  = 0.1f;
static constexpr float LAMBD_C = 0.5f;

// ---------------------------------------------------------------------------
// Input dtype detection: sample first 256 words of x. If the data is fp32,
// fp32-interpretation is ~100% "sane" while bf16-pair interpretation is ~55%.
// If the data is bf16, fp32-interpretation blows up (exponent bits come from
// a bf16's exp/mantissa -> ~1e37 or NaN). flag=1 -> fp32 inputs, 0 -> bf16.
// ---------------------------------------------------------------------------
__device__ __forceinline__ int sane_f(float v) {
    float a = fabsf(v);
    return (a <= 1.0e4f && (a >= 1.0e-6f || v == 0.0f)) ? 1 : 0;   // NaN -> 0
}

__global__ void detect_dtype(const unsigned int* __restrict__ words,
                             int* __restrict__ flag) {
    __shared__ int s32, s16;
    if (threadIdx.x == 0) { s32 = 0; s16 = 0; }
    __syncthreads();
    const unsigned int w = words[threadIdx.x];
    const float f  = __uint_as_float(w);
    const float h0 = __uint_as_float((w & 0xFFFFu) << 16);
    const float h1 = __uint_as_float(w & 0xFFFF0000u);
    atomicAdd(&s32, sane_f(f));
    atomicAdd(&s16, sane_f(h0) + sane_f(h1));
    __syncthreads();
    if (threadIdx.x == 0) flag[0] = (2 * s32 >= s16) ? 1 : 0;
}

// Canonicalize an input tensor to bf16 (cast from fp32 or copy bf16).
__global__ __launch_bounds__(256) void convert_bf16(const void* __restrict__ src,
                                                    HBF* __restrict__ dst, int n,
                                                    const int* __restrict__ flag) {
    const int f = *flag;
    int i = blockIdx.x * 256 + threadIdx.x;
    const int stride = gridDim.x * 256;
    if (f) {
        const float* s = (const float*)src;
        for (; i < n; i += stride) dst[i] = __float2bfloat16(s[i]);
    } else {
        const HBF* s = (const HBF*)src;
        for (; i < n; i += stride) dst[i] = s[i];
    }
}

// ---------------------------------------------------------------------------
// bf16 GEMM, B^T layout:  C[m,n] = sum_k A[m,k]*B[n,k] (+bias[n])
// 64x64 tile, 256 thr = 4 waves (2x2), MFMA 16x16x32 bf16.
// FINAL: output dtype chosen at runtime by *flagp (1->fp32, 0->bf16).
// !FINAL: output fp32.
// ---------------------------------------------------------------------------
template <bool BIAS, bool FINAL>
__global__ __launch_bounds__(256) void gemm_bt(const HBF* __restrict__ A,
                                               const HBF* __restrict__ B,
                                               const HBF* __restrict__ bias,
                                               void* __restrict__ Cout,
                                               int M, int N, int K,
                                               const int* __restrict__ flagp) {
    constexpr int LK = 40;  // 32 + 8 bf16 pad
    __shared__ HBF As[64 * LK];
    __shared__ HBF Bs[64 * LK];

    int outf32 = 1;
    if (FINAL) outf32 = *flagp;

    const int tid  = threadIdx.x;
    const int m0   = blockIdx.x * 64;
    const int n0   = blockIdx.y * 64;
    const int lane = tid & 63;
    const int wave = tid >> 6;
    const int wr = wave >> 1, wc = wave & 1;
    const int l15 = lane & 15, quad = lane >> 4;

    f32x4 acc[2][2] = {};

    const int ldrow = tid >> 2;
    const int ldcol = (tid & 3) * 8;

    for (int k0 = 0; k0 < K; k0 += 32) {
        uint4 va = *(const uint4*)(A + (size_t)(m0 + ldrow) * K + k0 + ldcol);
        uint4 vb = *(const uint4*)(B + (size_t)(n0 + ldrow) * K + k0 + ldcol);
        *(uint4*)(As + ldrow * LK + ldcol) = va;
        *(uint4*)(Bs + ldrow * LK + ldcol) = vb;
        __syncthreads();

        bf16x8 af[2], bfr[2];
#pragma unroll
        for (int i = 0; i < 2; i++)
            af[i] = *reinterpret_cast<const bf16x8*>(&As[(wr * 32 + i * 16 + l15) * LK + quad * 8]);
#pragma unroll
        for (int j = 0; j < 2; j++)
            bfr[j] = *reinterpret_cast<const bf16x8*>(&Bs[(wc * 32 + j * 16 + l15) * LK + quad * 8]);
#pragma unroll
        for (int i = 0; i < 2; i++)
#pragma unroll
            for (int j = 0; j < 2; j++)
                acc[i][j] = __builtin_amdgcn_mfma_f32_16x16x32_bf16(af[i], bfr[j], acc[i][j], 0, 0, 0);
        __syncthreads();
    }

#pragma unroll
    for (int i = 0; i < 2; i++)
#pragma unroll
        for (int j = 0; j < 2; j++) {
            const int col = n0 + wc * 32 + j * 16 + l15;
            float bval = 0.f;
            if (BIAS) bval = __bfloat162float(bias[col]);
#pragma unroll
            for (int r = 0; r < 4; r++) {
                const int row = m0 + wr * 32 + i * 16 + quad * 4 + r;
                const float v = acc[i][j][r] + bval;
                const size_t idx = (size_t)row * N + col;
                if (!FINAL) {
                    ((float*)Cout)[idx] = v;
                } else if (outf32) {
                    ((float*)Cout)[idx] = v;
                } else {
                    ((HBF*)Cout)[idx] = __float2bfloat16(v);
                }
            }
        }
}

// ---------------------------------------------------------------------------
// Split qkv [4096,2304] fp32 into Qn/Kn (L2-normalized bf16) and V (fp32),
// laid out [B*H, N, 64]. One wave per (bn, t, h).
// ---------------------------------------------------------------------------
__global__ __launch_bounds__(256) void normalize_split(const float* __restrict__ qkv,
                                                       HBF* __restrict__ Qn,
                                                       HBF* __restrict__ Kn,
                                                       float* __restrict__ Vf) {
    const int tid = threadIdx.x;
    const int wave = tid >> 6, lane = tid & 63;
    const int row_id = blockIdx.x * 4 + wave;  // 0 .. 4096*36-1
    const int bn = row_id / 36;
    const int th = row_id % 36;
    const int t = th / 12, h = th % 12;
    const int b = bn >> 11, n = bn & 2047;

    const float val = qkv[(size_t)bn * 2304 + t * 768 + h * 64 + lane];
    const size_t oidx = ((size_t)(b * 12 + h) * 2048 + n) * 64 + lane;

    if (t == 2) {
        Vf[oidx] = val;
    } else {
        float ss = val * val;
#pragma unroll
        for (int off = 32; off >= 1; off >>= 1) ss += __shfl_xor(ss, off, 64);
        const float sc = val / fmaxf(sqrtf(ss), 1e-12f);
        if (t == 0) Qn[oidx] = __float2bfloat16(sc);
        else        Kn[oidx] = __float2bfloat16(sc);
    }
}

// ---------------------------------------------------------------------------
// Gram matrices per (b,h): Mkv = Kn^T V, Mqv = Qn^T V, Mqq = Qn^T Qn (64x64).
// grid = (24 heads, 8 chunks of 256 rows); fp32 atomics into pre-zeroed M.
// ---------------------------------------------------------------------------
__global__ __launch_bounds__(256) void gram_mats(const HBF* __restrict__ Qn,
                                                 const HBF* __restrict__ Kn,
                                                 const float* __restrict__ Vf,
                                                 float* __restrict__ M) {
    const int bh = blockIdx.x;
    const int chunk = blockIdx.y;
    const int t = threadIdx.x;
    __shared__ float Qs[16 * 64], Ks[16 * 64], Vs[16 * 64];
    const int ti = t >> 4, tj = t & 15;

    float akv[4][4] = {}, aqv[4][4] = {}, aqq[4][4] = {};
    const size_t base = (size_t)bh * 2048 + chunk * 256;

    for (int sc = 0; sc < 16; sc++) {
        __syncthreads();
#pragma unroll
        for (int r = 0; r < 4; r++) {
            const int e = t + 256 * r;
            const int row = e >> 6, col = e & 63;
            const size_t g = (base + sc * 16 + row) * 64 + col;
            Qs[e] = __bfloat162float(Qn[g]);
            Ks[e] = __bfloat162float(Kn[g]);
            Vs[e] = Vf[g];
        }
        __syncthreads();
#pragma unroll
        for (int nn = 0; nn < 16; nn++) {
            float qi[4], ki[4], vj[4], qj[4];
#pragma unroll
            for (int a = 0; a < 4; a++) {
                qi[a] = Qs[nn * 64 + ti + 16 * a];
                ki[a] = Ks[nn * 64 + ti + 16 * a];
                vj[a] = Vs[nn * 64 + tj + 16 * a];
                qj[a] = Qs[nn * 64 + tj + 16 * a];
            }
#pragma unroll
            for (int a = 0; a < 4; a++)
#pragma unroll
                for (int c = 0; c < 4; c++) {
                    akv[a][c] += ki[a] * vj[c];
                    aqv[a][c] += qi[a] * vj[c];
                    aqq[a][c] += qi[a] * qj[c];
                }
        }
    }

    float* Mb = M + (size_t)bh * 3 * 4096;
#pragma unroll
    for (int a = 0; a < 4; a++)
#pragma unroll
        for (int c = 0; c < 4; c++) {
            const int i = ti + 16 * a, j = tj + 16 * c;
            atomicAdd(&Mb[i * 64 + j], akv[a][c]);
            atomicAdd(&Mb[4096 + i * 64 + j], aqv[a][c]);
            atomicAdd(&Mb[8192 + i * 64 + j], aqq[a][c]);
        }
}

// ---------------------------------------------------------------------------
// W = 0.1*s*Mqv - 0.1*s^2 * (Mqq @ Mkv)   per head (64x64)
// ---------------------------------------------------------------------------
__global__ __launch_bounds__(256) void combine_w(const float* __restrict__ M,
                                                 float* __restrict__ W) {
    const int bh = blockIdx.x;
    const int t = threadIdx.x;
    __shared__ float Kv[4096], Qq[4096];
    const float* Mb = M + (size_t)bh * 3 * 4096;
#pragma unroll
    for (int r = 0; r < 16; r++) {
        Kv[t + 256 * r] = Mb[t + 256 * r];
        Qq[t + 256 * r] = Mb[8192 + t + 256 * r];
    }
    __syncthreads();
    const int ti = t >> 4, tj = t & 15;
#pragma unroll
    for (int a = 0; a < 4; a++)
#pragma unroll
        for (int c = 0; c < 4; c++) {
            const int i = ti + 16 * a, j = tj + 16 * c;
            float s = 0.f;
            for (int k = 0; k < 64; k++) s += Qq[i * 64 + k] * Kv[k * 64 + j];
            W[(size_t)bh * 4096 + i * 64 + j] =
                STEP_C * (SCALE_C * Mb[4096 + i * 64 + j] - SCALE_C * SCALE_C * s);
        }
}

// ---------------------------------------------------------------------------
// AO[b, n, h*64+d] = relu(V[bh,n,d] + (Kn[bh,n,:] @ W[bh])[d] - 0.05), bf16
// ---------------------------------------------------------------------------
__global__ __launch_bounds__(256) void epilogue_attn(const HBF* __restrict__ Kn,
                                                     const float* __restrict__ Vf,
                                                     const float* __restrict__ W,
                                                     HBF* __restrict__ AO) {
    const int bh = blockIdx.x;
    const int nc = blockIdx.y;
    const int b = bh / 12, h = bh % 12;
    const int t = threadIdx.x;
    __shared__ float Ws[4096], Ks[4096];
    const float* Wb = W + (size_t)bh * 4096;
    const size_t kbase = ((size_t)bh * 2048 + nc * 64) * 64;
#pragma unroll
    for (int r = 0; r < 16; r++) {
        Ws[t + 256 * r] = Wb[t + 256 * r];
        Ks[t + 256 * r] = __bfloat162float(Kn[kbase + t + 256 * r]);
    }
    __syncthreads();
    const int nl = t >> 6, d = t & 63;
#pragma unroll
    for (int rep = 0; rep < 16; rep++) {
        const int n = rep * 4 + nl;
        float acc = 0.f;
        for (int k = 0; k < 64; k++) acc += Ks[n * 64 + k] * Ws[k * 64 + d];
        float v = Vf[kbase + (size_t)n * 64 + d] + acc - (STEP_C * LAMBD_C);
        AO[((size_t)b * 2048 + nc * 64 + n) * 768 + h * 64 + d] = __float2bfloat16(fmaxf(v, 0.f));
    }
}

// ---------------------------------------------------------------------------
extern "C" void kernel_launch(void* const* d_in, const int* in_sizes, int n_in,
                              void* d_out, int out_size, void* d_ws, size_t ws_size,
                              hipStream_t stream) {
    char* ws = (char*)d_ws;
    size_t off = 0;
    int*   flag   = (int*)(ws + off);   off += 16;
    HBF*   xb     = (HBF*)(ws + off);   off += (size_t)4096 * 768 * 2;
    HBF*   Wqkvb  = (HBF*)(ws + off);   off += (size_t)2304 * 768 * 2;
    HBF*   Wprojb = (HBF*)(ws + off);   off += (size_t)768 * 768 * 2;
    HBF*   bprojb = (HBF*)(ws + off);   off += 2048;
    float* qkv    = (float*)(ws + off); off += (size_t)4096 * 2304 * 4;
    HBF*   Qn     = (HBF*)(ws + off);   off += (size_t)24 * 2048 * 64 * 2;
    HBF*   Kn     = (HBF*)(ws + off);   off += (size_t)24 * 2048 * 64 * 2;
    float* Vf     = (float*)(ws + off); off += (size_t)24 * 2048 * 64 * 4;
    float* M      = (float*)(ws + off); off += (size_t)24 * 3 * 4096 * 4;
    float* W      = (float*)(ws + off); off += (size_t)24 * 4096 * 4;
    HBF*   AO     = (HBF*)(ws + off);   off += (size_t)4096 * 768 * 2;
    // total ~82 MB

    // 0) dtype detect + canonicalize inputs to bf16
    detect_dtype<<<1, 256, 0, stream>>>((const unsigned int*)d_in[0], flag);
    convert_bf16<<<1024, 256, 0, stream>>>(d_in[0], xb,     4096 * 768,  flag);
    convert_bf16<<<1024, 256, 0, stream>>>(d_in[1], Wqkvb,  2304 * 768,  flag);
    convert_bf16<<<512,  256, 0, stream>>>(d_in[2], Wprojb, 768 * 768,   flag);
    convert_bf16<<<3,    256, 0, stream>>>(d_in[3], bprojb, 768,         flag);

    hipMemsetAsync(M, 0, (size_t)24 * 3 * 4096 * 4, stream);

    // 1) qkv = x @ Wqkv^T -> fp32 [4096,2304]
    gemm_bt<false, false><<<dim3(64, 36), 256, 0, stream>>>(xb, Wqkvb, nullptr, qkv,
                                                            4096, 2304, 768, nullptr);
    // 2) split + L2-normalize q,k
    normalize_split<<<36864, 256, 0, stream>>>(qkv, Qn, Kn, Vf);
    // 3) 64x64 Gram matrices per head
    gram_mats<<<dim3(24, 8), 256, 0, stream>>>(Qn, Kn, Vf, M);
    // 4) W combine
    combine_w<<<24, 256, 0, stream>>>(M, W);
    // 5) relu(V + Kn@W - 0.05) -> [B,N,C] bf16
    epilogue_attn<<<dim3(24, 32), 256, 0, stream>>>(Kn, Vf, W, AO);
    // 6) out = AO @ Wproj^T + bproj, dtype per flag
    gemm_bt<true, true><<<dim3(64, 12), 256, 0, stream>>>(AO, Wprojb, bprojb, d_out,
                                                          4096, 768, 768, flag);
}

// Round 3
// 300.884 us; speedup vs baseline: 1.0277x; 1.0277x over previous
//
#include <hip/hip_runtime.h>
#include <hip/hip_bf16.h>

typedef __attribute__((ext_vector_type(8))) __bf16 bf16x8;
typedef __attribute__((ext_vector_type(4))) float f32x4;

#define HBF __hip_bfloat16

// B=2, N=2048, C=768, H=12, D=64
static constexpr float SCALE_C = 0.125f;   // D^-0.5
static constexpr float STEP_C  = 0.1f;
static constexpr float LAMBD_C = 0.5f;

// ---------------------------------------------------------------------------
// Input dtype detection (fp32 vs bf16 inputs). flag=1 -> fp32, 0 -> bf16.
// ---------------------------------------------------------------------------
__device__ __forceinline__ int sane_f(float v) {
    float a = fabsf(v);
    return (a <= 1.0e4f && (a >= 1.0e-6f || v == 0.0f)) ? 1 : 0;   // NaN -> 0
}

__global__ void detect_dtype(const unsigned int* __restrict__ words,
                             int* __restrict__ flag) {
    __shared__ int s32, s16;
    if (threadIdx.x == 0) { s32 = 0; s16 = 0; }
    __syncthreads();
    const unsigned int w = words[threadIdx.x];
    const float f  = __uint_as_float(w);
    const float h0 = __uint_as_float((w & 0xFFFFu) << 16);
    const float h1 = __uint_as_float(w & 0xFFFF0000u);
    atomicAdd(&s32, sane_f(f));
    atomicAdd(&s16, sane_f(h0) + sane_f(h1));
    __syncthreads();
    if (threadIdx.x == 0) flag[0] = (2 * s32 >= s16) ? 1 : 0;
}

__global__ __launch_bounds__(256) void convert_bf16(const void* __restrict__ src,
                                                    HBF* __restrict__ dst, int n,
                                                    const int* __restrict__ flag) {
    const int f = *flag;
    int i = blockIdx.x * 256 + threadIdx.x;
    const int stride = gridDim.x * 256;
    if (f) {
        const float* s = (const float*)src;
        for (; i < n; i += stride) dst[i] = __float2bfloat16(s[i]);
    } else {
        const HBF* s = (const HBF*)src;
        for (; i < n; i += stride) dst[i] = s[i];
    }
}

// ---------------------------------------------------------------------------
// m97-style bf16 GEMM, B^T layout: C[m,n] = sum_k A[m,k]*B[n,k] (+bias[n])
// 128x128 tile, BK=64, 256 thr = 4 waves (2x2), each wave 64x64 via 4x4 MFMAs.
// Staging via global_load_lds width=16 with XOR chunk swizzle (bank-friendly).
// FINAL: out dtype per runtime flag (1->fp32, 0->bf16); else bf16.
// ---------------------------------------------------------------------------
template <bool BIAS, bool FINAL>
__global__ __launch_bounds__(256) void gemm128(const HBF* __restrict__ A,
                                               const HBF* __restrict__ B,
                                               const HBF* __restrict__ bias,
                                               void* __restrict__ Cout,
                                               int M, int N, int K,
                                               const int* __restrict__ flagp) {
    __shared__ HBF As[128 * 64];
    __shared__ HBF Bs[128 * 64];

    int outf32 = 0;
    if (FINAL) outf32 = *flagp;

    const int tid  = threadIdx.x;
    const int wv   = tid >> 6, lane = tid & 63;
    const int m0   = blockIdx.x * 128, n0 = blockIdx.y * 128;
    const int wr = wv >> 1, wc = wv & 1;
    const int l15 = lane & 15, quad = lane >> 4;

    // staging geometry: each wave-dispatch covers 8 rows (1 KB of LDS)
    const int srow   = lane >> 3;              // 0..7 row within region
    const int schunk = (lane & 7) ^ srow;      // XOR-swizzled 16B chunk

    f32x4 acc[4][4] = {};

    for (int k0 = 0; k0 < K; k0 += 64) {
#pragma unroll
        for (int d = 0; d < 4; d++) {
            const int region = d * 4 + wv;     // 0..15, 8 rows each
            const int row = region * 8 + srow;
            const HBF* ga = A + (size_t)(m0 + row) * K + k0 + schunk * 8;
            const HBF* gb = B + (size_t)(n0 + row) * K + k0 + schunk * 8;
            __builtin_amdgcn_global_load_lds((const void*)ga, (void*)(As + region * 512), 16, 0, 0);
            __builtin_amdgcn_global_load_lds((const void*)gb, (void*)(Bs + region * 512), 16, 0, 0);
        }
        __syncthreads();   // drains vmcnt -> LDS tiles complete

#pragma unroll
        for (int s = 0; s < 2; s++) {
            bf16x8 af[4], bfr[4];
#pragma unroll
            for (int i = 0; i < 4; i++) {
                const int row = wr * 64 + i * 16 + l15;
                const int ch = (s * 4 + quad) ^ (row & 7);
                af[i] = *reinterpret_cast<const bf16x8*>(&As[row * 64 + ch * 8]);
            }
#pragma unroll
            for (int j = 0; j < 4; j++) {
                const int col = wc * 64 + j * 16 + l15;
                const int ch = (s * 4 + quad) ^ (col & 7);
                bfr[j] = *reinterpret_cast<const bf16x8*>(&Bs[col * 64 + ch * 8]);
            }
#pragma unroll
            for (int i = 0; i < 4; i++)
#pragma unroll
                for (int j = 0; j < 4; j++)
                    acc[i][j] = __builtin_amdgcn_mfma_f32_16x16x32_bf16(af[i], bfr[j], acc[i][j], 0, 0, 0);
        }
        __syncthreads();
    }

#pragma unroll
    for (int i = 0; i < 4; i++)
#pragma unroll
        for (int j = 0; j < 4; j++) {
            const int col = n0 + wc * 64 + j * 16 + l15;
            float bval = 0.f;
            if (BIAS) bval = __bfloat162float(bias[col]);
#pragma unroll
            for (int r = 0; r < 4; r++) {
                const int row = m0 + wr * 64 + i * 16 + quad * 4 + r;
                const float v = acc[i][j][r] + bval;
                const size_t idx = (size_t)row * N + col;
                if (!FINAL) {
                    ((HBF*)Cout)[idx] = __float2bfloat16(v);
                } else if (outf32) {
                    ((float*)Cout)[idx] = v;
                } else {
                    ((HBF*)Cout)[idx] = __float2bfloat16(v);
                }
            }
        }
}

// ---------------------------------------------------------------------------
// Split qkv [4096,2304] bf16 into Qn/Kn (L2-normalized bf16) and Vb (bf16),
// laid out [B*H, N, 64]. One wave per (bn, t, h).
// ---------------------------------------------------------------------------
__global__ __launch_bounds__(256) void normalize_split(const HBF* __restrict__ qkvb,
                                                       HBF* __restrict__ Qn,
                                                       HBF* __restrict__ Kn,
                                                       HBF* __restrict__ Vb) {
    const int tid = threadIdx.x;
    const int wave = tid >> 6, lane = tid & 63;
    const int row_id = blockIdx.x * 4 + wave;  // 0 .. 4096*36-1
    const int bn = row_id / 36;
    const int th = row_id % 36;
    const int t = th / 12, h = th % 12;
    const int b = bn >> 11, n = bn & 2047;

    const HBF raw = qkvb[(size_t)bn * 2304 + t * 768 + h * 64 + lane];
    const size_t oidx = ((size_t)(b * 12 + h) * 2048 + n) * 64 + lane;

    if (t == 2) {
        Vb[oidx] = raw;
    } else {
        const float val = __bfloat162float(raw);
        float ss = val * val;
#pragma unroll
        for (int off = 32; off >= 1; off >>= 1) ss += __shfl_xor(ss, off, 64);
        const float sc = val / fmaxf(sqrtf(ss), 1e-12f);
        if (t == 0) Qn[oidx] = __float2bfloat16(sc);
        else        Kn[oidx] = __float2bfloat16(sc);
    }
}

// ---------------------------------------------------------------------------
// Gram matrices per (b,h): Mkv = Kn^T V, Mqv = Qn^T V, Mqq = Qn^T Qn (64x64).
// grid = (24, 64 chunks of 32 rows); fp32 atomics into pre-zeroed M.
// ---------------------------------------------------------------------------
__global__ __launch_bounds__(256) void gram_mats(const HBF* __restrict__ Qn,
                                                 const HBF* __restrict__ Kn,
                                                 const HBF* __restrict__ Vb,
                                                 float* __restrict__ M) {
    const int bh = blockIdx.x;
    const int cn = blockIdx.y;
    const int t = threadIdx.x;
    __shared__ float Qs[2048], Ks[2048], Vs[2048];
    const int ti = t >> 4, tj = t & 15;
    const size_t gbase = ((size_t)bh * 2048 + cn * 32) * 64;

#pragma unroll
    for (int r = 0; r < 8; r++) {
        const int e = t + 256 * r;
        Qs[e] = __bfloat162float(Qn[gbase + e]);
        Ks[e] = __bfloat162float(Kn[gbase + e]);
        Vs[e] = __bfloat162float(Vb[gbase + e]);
    }
    __syncthreads();

    float akv[4][4] = {}, aqv[4][4] = {}, aqq[4][4] = {};
#pragma unroll 4
    for (int nn = 0; nn < 32; nn++) {
        float qi[4], ki[4], vj[4], qj[4];
#pragma unroll
        for (int a = 0; a < 4; a++) {
            qi[a] = Qs[nn * 64 + ti + 16 * a];
            ki[a] = Ks[nn * 64 + ti + 16 * a];
            vj[a] = Vs[nn * 64 + tj + 16 * a];
            qj[a] = Qs[nn * 64 + tj + 16 * a];
        }
#pragma unroll
        for (int a = 0; a < 4; a++)
#pragma unroll
            for (int c = 0; c < 4; c++) {
                akv[a][c] += ki[a] * vj[c];
                aqv[a][c] += qi[a] * vj[c];
                aqq[a][c] += qi[a] * qj[c];
            }
    }

    float* Mb = M + (size_t)bh * 3 * 4096;
#pragma unroll
    for (int a = 0; a < 4; a++)
#pragma unroll
        for (int c = 0; c < 4; c++) {
            const int i = ti + 16 * a, j = tj + 16 * c;
            atomicAdd(&Mb[i * 64 + j], akv[a][c]);
            atomicAdd(&Mb[4096 + i * 64 + j], aqv[a][c]);
            atomicAdd(&Mb[8192 + i * 64 + j], aqq[a][c]);
        }
}

// ---------------------------------------------------------------------------
// W = 0.1*s*Mqv - 0.1*s^2 * (Mqq @ Mkv)  per head. grid (24, 8 row-groups).
// ---------------------------------------------------------------------------
__global__ __launch_bounds__(256) void combine_w(const float* __restrict__ M,
                                                 float* __restrict__ W) {
    const int bh = blockIdx.x;
    const int by = blockIdx.y;     // 0..7 -> rows by*8..+8
    const int t = threadIdx.x;
    __shared__ float Kv[4096];
    __shared__ float Qq8[512];
    const float* Mb = M + (size_t)bh * 12288;
#pragma unroll
    for (int r = 0; r < 16; r++) Kv[t + 256 * r] = Mb[t + 256 * r];
#pragma unroll
    for (int r = 0; r < 2; r++)  Qq8[t + 256 * r] = Mb[8192 + by * 512 + t + 256 * r];
    __syncthreads();

    const int il = t >> 5;            // 0..7
    const int j0 = (t & 31) * 2;
    float s0 = 0.f, s1 = 0.f;
#pragma unroll
    for (int k = 0; k < 64; k++) {
        const float q = Qq8[il * 64 + k];
        const float2 kv = *(const float2*)&Kv[k * 64 + j0];
        s0 += q * kv.x;
        s1 += q * kv.y;
    }
    const int i = by * 8 + il;
    const size_t o = (size_t)bh * 4096 + i * 64 + j0;
    W[o]     = STEP_C * (SCALE_C * Mb[4096 + i * 64 + j0]     - SCALE_C * SCALE_C * s0);
    W[o + 1] = STEP_C * (SCALE_C * Mb[4096 + i * 64 + j0 + 1] - SCALE_C * SCALE_C * s1);
}

// ---------------------------------------------------------------------------
// AO[b, n, h*64+d] = relu(V[bh,n,d] + (Kn[bh,n,:] @ W[bh])[d] - 0.05), bf16.
// W column cached in 64 registers; K rows via wave-uniform float4 broadcasts.
// ---------------------------------------------------------------------------
__global__ __launch_bounds__(256) void epilogue_attn(const HBF* __restrict__ Kn,
                                                     const HBF* __restrict__ Vb,
                                                     const float* __restrict__ W,
                                                     HBF* __restrict__ AO) {
    const int bh = blockIdx.x;
    const int nc = blockIdx.y;
    const int b = bh / 12, h = bh % 12;
    const int t = threadIdx.x;
    __shared__ float Ws[4096];
    __shared__ float Ks[4096];
    const float* Wb = W + (size_t)bh * 4096;
    const size_t kbase = ((size_t)bh * 2048 + nc * 64) * 64;
#pragma unroll
    for (int r = 0; r < 16; r++) {
        Ws[t + 256 * r] = Wb[t + 256 * r];
        Ks[t + 256 * r] = __bfloat162float(Kn[kbase + t + 256 * r]);
    }
    __syncthreads();

    const int nl = t >> 6, d = t & 63;
    float wcol[64];
#pragma unroll
    for (int k = 0; k < 64; k++) wcol[k] = Ws[k * 64 + d];   // stride-64: 2-way, free

#pragma unroll
    for (int rep = 0; rep < 16; rep++) {
        const int n = rep * 4 + nl;
        float acc = 0.f;
#pragma unroll
        for (int k4 = 0; k4 < 16; k4++) {
            const float4 kv = *(const float4*)&Ks[n * 64 + k4 * 4];   // broadcast
            acc += kv.x * wcol[k4 * 4] + kv.y * wcol[k4 * 4 + 1]
                 + kv.z * wcol[k4 * 4 + 2] + kv.w * wcol[k4 * 4 + 3];
        }
        float v = __bfloat162float(Vb[kbase + (size_t)n * 64 + d]) + acc - (STEP_C * LAMBD_C);
        AO[((size_t)b * 2048 + nc * 64 + n) * 768 + h * 64 + d] = __float2bfloat16(fmaxf(v, 0.f));
    }
}

// ---------------------------------------------------------------------------
extern "C" void kernel_launch(void* const* d_in, const int* in_sizes, int n_in,
                              void* d_out, int out_size, void* d_ws, size_t ws_size,
                              hipStream_t stream) {
    char* ws = (char*)d_ws;
    size_t off = 0;
    int*   flag   = (int*)(ws + off);   off += 16;
    HBF*   xb     = (HBF*)(ws + off);   off += (size_t)4096 * 768 * 2;
    HBF*   Wqkvb  = (HBF*)(ws + off);   off += (size_t)2304 * 768 * 2;
    HBF*   Wprojb = (HBF*)(ws + off);   off += (size_t)768 * 768 * 2;
    HBF*   bprojb = (HBF*)(ws + off);   off += 2048;
    HBF*   qkvb   = (HBF*)(ws + off);   off += (size_t)4096 * 2304 * 2;
    HBF*   Qn     = (HBF*)(ws + off);   off += (size_t)24 * 2048 * 64 * 2;
    HBF*   Kn     = (HBF*)(ws + off);   off += (size_t)24 * 2048 * 64 * 2;
    HBF*   Vb     = (HBF*)(ws + off);   off += (size_t)24 * 2048 * 64 * 2;
    float* M      = (float*)(ws + off); off += (size_t)24 * 3 * 4096 * 4;
    float* W      = (float*)(ws + off); off += (size_t)24 * 4096 * 4;
    HBF*   AO     = (HBF*)(ws + off);   off += (size_t)4096 * 768 * 2;
    // total ~52 MB

    // 0) dtype detect + canonicalize inputs to bf16
    detect_dtype<<<1, 256, 0, stream>>>((const unsigned int*)d_in[0], flag);
    convert_bf16<<<1024, 256, 0, stream>>>(d_in[0], xb,     4096 * 768,  flag);
    convert_bf16<<<1024, 256, 0, stream>>>(d_in[1], Wqkvb,  2304 * 768,  flag);
    convert_bf16<<<512,  256, 0, stream>>>(d_in[2], Wprojb, 768 * 768,   flag);
    convert_bf16<<<3,    256, 0, stream>>>(d_in[3], bprojb, 768,         flag);

    hipMemsetAsync(M, 0, (size_t)24 * 3 * 4096 * 4, stream);

    // 1) qkv = x @ Wqkv^T -> bf16 [4096,2304]
    gemm128<false, false><<<dim3(32, 18), 256, 0, stream>>>(xb, Wqkvb, nullptr, qkvb,
                                                            4096, 2304, 768, nullptr);
    // 2) split + L2-normalize q,k
    normalize_split<<<36864, 256, 0, stream>>>(qkvb, Qn, Kn, Vb);
    // 3) 64x64 Gram matrices per head
    gram_mats<<<dim3(24, 64), 256, 0, stream>>>(Qn, Kn, Vb, M);
    // 4) W combine
    combine_w<<<dim3(24, 8), 256, 0, stream>>>(M, W);
    // 5) relu(V + Kn@W - 0.05) -> [B,N,C] bf16
    epilogue_attn<<<dim3(24, 32), 256, 0, stream>>>(Kn, Vb, W, AO);
    // 6) out = AO @ Wproj^T + bproj, dtype per flag
    gemm128<true, true><<<dim3(32, 6), 256, 0, stream>>>(AO, Wprojb, bprojb, d_out,
                                                         4096, 768, 768, flag);
}

// Round 4
// 192.932 us; speedup vs baseline: 1.6027x; 1.5595x over previous
//
#include <hip/hip_runtime.h>
#include <hip/hip_bf16.h>

typedef __attribute__((ext_vector_type(8))) __bf16 bf16x8;
typedef __attribute__((ext_vector_type(4))) float f32x4;

#define HBF __hip_bfloat16

// B=2, N=2048, C=768, H=12, D=64
static constexpr float SCALE_C = 0.125f;   // D^-0.5
static constexpr float STEP_C  = 0.1f;
static constexpr float LAMBD_C = 0.5f;

// ---------------------------------------------------------------------------
// Input dtype detection (fp32 vs bf16 inputs). flag=1 -> fp32, 0 -> bf16.
// ---------------------------------------------------------------------------
__device__ __forceinline__ int sane_f(float v) {
    float a = fabsf(v);
    return (a <= 1.0e4f && (a >= 1.0e-6f || v == 0.0f)) ? 1 : 0;   // NaN -> 0
}

__global__ void detect_dtype(const unsigned int* __restrict__ words,
                             int* __restrict__ flag) {
    __shared__ int s32, s16;
    if (threadIdx.x == 0) { s32 = 0; s16 = 0; }
    __syncthreads();
    const unsigned int w = words[threadIdx.x];
    const float f  = __uint_as_float(w);
    const float h0 = __uint_as_float((w & 0xFFFFu) << 16);
    const float h1 = __uint_as_float(w & 0xFFFF0000u);
    atomicAdd(&s32, sane_f(f));
    atomicAdd(&s16, sane_f(h0) + sane_f(h1));
    __syncthreads();
    if (threadIdx.x == 0) flag[0] = (2 * s32 >= s16) ? 1 : 0;
}

__global__ __launch_bounds__(256) void convert_bf16(const void* __restrict__ src,
                                                    HBF* __restrict__ dst, int n,
                                                    const int* __restrict__ flag) {
    const int f = *flag;
    int i = blockIdx.x * 256 + threadIdx.x;
    const int stride = gridDim.x * 256;
    if (f) {
        const float* s = (const float*)src;
        for (; i < n; i += stride) dst[i] = __float2bfloat16(s[i]);
    } else {
        const HBF* s = (const HBF*)src;
        for (; i < n; i += stride) dst[i] = s[i];
    }
}

// ---------------------------------------------------------------------------
// m97-style bf16 GEMM, B^T layout: C[m,n] = sum_k A[m,k]*B[n,k] (+bias[n])
// 128x128 tile, BK=64, 256 thr = 4 waves (2x2), wave does 64x64 via 4x4 MFMA.
// global_load_lds width=16 staging with XOR chunk swizzle.
// SPLITQKV: scatter into head-split layout (Qraw/Kraw/Vb [bh][n][64], bf16).
// FINAL: out dtype per runtime flag (1->fp32, 0->bf16).
// ---------------------------------------------------------------------------
template <bool BIAS, bool FINAL, bool SPLITQKV>
__global__ __launch_bounds__(256) void gemm128(const HBF* __restrict__ A,
                                               const HBF* __restrict__ B,
                                               const HBF* __restrict__ bias,
                                               void* __restrict__ Cout,
                                               HBF* __restrict__ qraw,   // [2][24][2048][64] (Q then K)
                                               HBF* __restrict__ vbuf,   // [24][2048][64]
                                               int M, int N, int K,
                                               const int* __restrict__ flagp) {
    __shared__ HBF As[128 * 64];
    __shared__ HBF Bs[128 * 64];

    int outf32 = 0;
    if (FINAL) outf32 = *flagp;

    const int tid  = threadIdx.x;
    const int wv   = tid >> 6, lane = tid & 63;
    const int m0   = blockIdx.x * 128, n0 = blockIdx.y * 128;
    const int wr = wv >> 1, wc = wv & 1;
    const int l15 = lane & 15, quad = lane >> 4;

    const int srow   = lane >> 3;              // 0..7 row within region
    const int schunk = (lane & 7) ^ srow;      // XOR-swizzled 16B chunk

    f32x4 acc[4][4] = {};

    for (int k0 = 0; k0 < K; k0 += 64) {
#pragma unroll
        for (int d = 0; d < 4; d++) {
            const int region = d * 4 + wv;     // 0..15, 8 rows each
            const int row = region * 8 + srow;
            const HBF* ga = A + (size_t)(m0 + row) * K + k0 + schunk * 8;
            const HBF* gb = B + (size_t)(n0 + row) * K + k0 + schunk * 8;
            __builtin_amdgcn_global_load_lds((const void*)ga, (void*)(As + region * 512), 16, 0, 0);
            __builtin_amdgcn_global_load_lds((const void*)gb, (void*)(Bs + region * 512), 16, 0, 0);
        }
        __syncthreads();

#pragma unroll
        for (int s = 0; s < 2; s++) {
            bf16x8 af[4], bfr[4];
#pragma unroll
            for (int i = 0; i < 4; i++) {
                const int row = wr * 64 + i * 16 + l15;
                const int ch = (s * 4 + quad) ^ (row & 7);
                af[i] = *reinterpret_cast<const bf16x8*>(&As[row * 64 + ch * 8]);
            }
#pragma unroll
            for (int j = 0; j < 4; j++) {
                const int col = wc * 64 + j * 16 + l15;
                const int ch = (s * 4 + quad) ^ (col & 7);
                bfr[j] = *reinterpret_cast<const bf16x8*>(&Bs[col * 64 + ch * 8]);
            }
#pragma unroll
            for (int i = 0; i < 4; i++)
#pragma unroll
                for (int j = 0; j < 4; j++)
                    acc[i][j] = __builtin_amdgcn_mfma_f32_16x16x32_bf16(af[i], bfr[j], acc[i][j], 0, 0, 0);
        }
        __syncthreads();
    }

#pragma unroll
    for (int i = 0; i < 4; i++)
#pragma unroll
        for (int j = 0; j < 4; j++) {
            const int col = n0 + wc * 64 + j * 16 + l15;
            float bval = 0.f;
            if (BIAS) bval = __bfloat162float(bias[col]);

            // split-head targeting (col fixed within this (i,j))
            int tsel = 0, hd = 0;
            HBF* tptr = nullptr;
            if (SPLITQKV) {
                tsel = (col >= 1536) ? 2 : ((col >= 768) ? 1 : 0);
                hd = col - tsel * 768;                 // h*64 + d
                tptr = (tsel == 2) ? vbuf : (qraw + (size_t)tsel * 24 * 2048 * 64);
            }
#pragma unroll
            for (int r = 0; r < 4; r++) {
                const int row = m0 + wr * 64 + i * 16 + quad * 4 + r;
                const float v = acc[i][j][r] + bval;
                if (SPLITQKV) {
                    const int b = row >> 11, n = row & 2047;
                    const int h = hd >> 6, d = hd & 63;
                    const size_t idx = ((size_t)(b * 12 + h) * 2048 + n) * 64 + d;
                    tptr[idx] = __float2bfloat16(v);
                } else {
                    const size_t idx = (size_t)row * N + col;
                    if (FINAL && outf32) ((float*)Cout)[idx] = v;
                    else                 ((HBF*)Cout)[idx] = __float2bfloat16(v);
                }
            }
        }
}

// ---------------------------------------------------------------------------
// L2-normalize rows of QKraw [2*24*2048][64] bf16 -> QKn (same indexing).
// 8 lanes per row, bf16x8 per lane. 32 rows per block.
// ---------------------------------------------------------------------------
__global__ __launch_bounds__(256) void normalize_qk(const HBF* __restrict__ QKraw,
                                                    HBF* __restrict__ QKn) {
    const int t = threadIdx.x;
    const size_t row = (size_t)blockIdx.x * 32 + (t >> 3);
    const int sub = t & 7;
    const size_t base = row * 64 + sub * 8;

    uint4 raw = *(const uint4*)(QKraw + base);
    const HBF* h = (const HBF*)&raw;
    float v[8];
    float ss = 0.f;
#pragma unroll
    for (int i = 0; i < 8; i++) { v[i] = __bfloat162float(h[i]); ss += v[i] * v[i]; }
#pragma unroll
    for (int off = 1; off <= 4; off <<= 1) ss += __shfl_xor(ss, off, 64);
    const float inv = 1.0f / fmaxf(sqrtf(ss), 1e-12f);

    HBF outv[8];
#pragma unroll
    for (int i = 0; i < 8; i++) outv[i] = __float2bfloat16(v[i] * inv);
    *(uint4*)(QKn + base) = *(const uint4*)outv;
}

// ---------------------------------------------------------------------------
// Gram partials per (head, chunk of 128 rows): Mkv, Mqv, Mqq (64x64 each).
// grid (24, 16); plain stores to private slab P[bh][cn][3*4096]. NO atomics.
// ---------------------------------------------------------------------------
__global__ __launch_bounds__(256) void gram_partial(const HBF* __restrict__ Qn,
                                                    const HBF* __restrict__ Kn,
                                                    const HBF* __restrict__ Vb,
                                                    float* __restrict__ P) {
    const int bh = blockIdx.x;
    const int cn = blockIdx.y;
    const int t = threadIdx.x;
    __shared__ float Qs[2048], Ks[2048], Vs[2048];
    const int ti = t >> 4, tj = t & 15;

    float akv[4][4] = {}, aqv[4][4] = {}, aqq[4][4] = {};

    for (int it = 0; it < 4; it++) {
        const size_t gbase = ((size_t)bh * 2048 + cn * 128 + it * 32) * 64 + t * 8;
        __syncthreads();
        {
            uint4 rq = *(const uint4*)(Qn + gbase);
            uint4 rk = *(const uint4*)(Kn + gbase);
            uint4 rv = *(const uint4*)(Vb + gbase);
            const HBF* hq = (const HBF*)&rq;
            const HBF* hk = (const HBF*)&rk;
            const HBF* hv = (const HBF*)&rv;
#pragma unroll
            for (int i = 0; i < 8; i++) {
                Qs[t * 8 + i] = __bfloat162float(hq[i]);
                Ks[t * 8 + i] = __bfloat162float(hk[i]);
                Vs[t * 8 + i] = __bfloat162float(hv[i]);
            }
        }
        __syncthreads();

#pragma unroll 4
        for (int nn = 0; nn < 32; nn++) {
            float qi[4], ki[4], vj[4], qj[4];
#pragma unroll
            for (int a = 0; a < 4; a++) {
                qi[a] = Qs[nn * 64 + ti + 16 * a];
                ki[a] = Ks[nn * 64 + ti + 16 * a];
                vj[a] = Vs[nn * 64 + tj + 16 * a];
                qj[a] = Qs[nn * 64 + tj + 16 * a];
            }
#pragma unroll
            for (int a = 0; a < 4; a++)
#pragma unroll
                for (int c = 0; c < 4; c++) {
                    akv[a][c] += ki[a] * vj[c];
                    aqv[a][c] += qi[a] * vj[c];
                    aqq[a][c] += qi[a] * qj[c];
                }
        }
    }

    float* Pb = P + ((size_t)bh * 16 + cn) * 12288;
#pragma unroll
    for (int a = 0; a < 4; a++)
#pragma unroll
        for (int c = 0; c < 4; c++) {
            const int i = ti + 16 * a, j = tj + 16 * c;
            Pb[i * 64 + j]        = akv[a][c];
            Pb[4096 + i * 64 + j] = aqv[a][c];
            Pb[8192 + i * 64 + j] = aqq[a][c];
        }
}

// Sum the 16 slabs per head: M[head][3*4096] = sum_s P[head][s][...]
__global__ __launch_bounds__(256) void gram_reduce(const float* __restrict__ P,
                                                   float* __restrict__ M) {
    const int o = blockIdx.x * 256 + threadIdx.x;   // 0..294911
    const int head = o / 12288, e = o % 12288;
    const float* Pb = P + (size_t)head * 16 * 12288 + e;
    float s = 0.f;
#pragma unroll
    for (int k = 0; k < 16; k++) s += Pb[(size_t)k * 12288];
    M[o] = s;
}

// ---------------------------------------------------------------------------
// W = 0.1*s*Mqv - 0.1*s^2 * (Mqq @ Mkv)  per head. grid (24, 8 row-groups).
// ---------------------------------------------------------------------------
__global__ __launch_bounds__(256) void combine_w(const float* __restrict__ M,
                                                 float* __restrict__ W) {
    const int bh = blockIdx.x;
    const int by = blockIdx.y;
    const int t = threadIdx.x;
    __shared__ float Kv[4096];
    __shared__ float Qq8[512];
    const float* Mb = M + (size_t)bh * 12288;
#pragma unroll
    for (int r = 0; r < 16; r++) Kv[t + 256 * r] = Mb[t + 256 * r];
#pragma unroll
    for (int r = 0; r < 2; r++)  Qq8[t + 256 * r] = Mb[8192 + by * 512 + t + 256 * r];
    __syncthreads();

    const int il = t >> 5;
    const int j0 = (t & 31) * 2;
    float s0 = 0.f, s1 = 0.f;
#pragma unroll
    for (int k = 0; k < 64; k++) {
        const float q = Qq8[il * 64 + k];
        const float2 kv = *(const float2*)&Kv[k * 64 + j0];
        s0 += q * kv.x;
        s1 += q * kv.y;
    }
    const int i = by * 8 + il;
    const size_t o = (size_t)bh * 4096 + i * 64 + j0;
    W[o]     = STEP_C * (SCALE_C * Mb[4096 + i * 64 + j0]     - SCALE_C * SCALE_C * s0);
    W[o + 1] = STEP_C * (SCALE_C * Mb[4096 + i * 64 + j0 + 1] - SCALE_C * SCALE_C * s1);
}

// ---------------------------------------------------------------------------
// AO[b, n, h*64+d] = relu(V[bh,n,d] + (Kn[bh,n,:] @ W[bh])[d] - 0.05), bf16.
// ---------------------------------------------------------------------------
__global__ __launch_bounds__(256) void epilogue_attn(const HBF* __restrict__ Kn,
                                                     const HBF* __restrict__ Vb,
                                                     const float* __restrict__ W,
                                                     HBF* __restrict__ AO) {
    const int bh = blockIdx.x;
    const int nc = blockIdx.y;
    const int b = bh / 12, h = bh % 12;
    const int t = threadIdx.x;
    __shared__ float Ws[4096];
    __shared__ float Ks[4096];
    const float* Wb = W + (size_t)bh * 4096;
    const size_t kbase = ((size_t)bh * 2048 + nc * 64) * 64;
#pragma unroll
    for (int r = 0; r < 16; r++) {
        Ws[t + 256 * r] = Wb[t + 256 * r];
        Ks[t + 256 * r] = __bfloat162float(Kn[kbase + t + 256 * r]);
    }
    __syncthreads();

    const int nl = t >> 6, d = t & 63;
    float wcol[64];
#pragma unroll
    for (int k = 0; k < 64; k++) wcol[k] = Ws[k * 64 + d];

#pragma unroll
    for (int rep = 0; rep < 16; rep++) {
        const int n = rep * 4 + nl;
        float acc = 0.f;
#pragma unroll
        for (int k4 = 0; k4 < 16; k4++) {
            const float4 kv = *(const float4*)&Ks[n * 64 + k4 * 4];
            acc += kv.x * wcol[k4 * 4] + kv.y * wcol[k4 * 4 + 1]
                 + kv.z * wcol[k4 * 4 + 2] + kv.w * wcol[k4 * 4 + 3];
        }
        float v = __bfloat162float(Vb[kbase + (size_t)n * 64 + d]) + acc - (STEP_C * LAMBD_C);
        AO[((size_t)b * 2048 + nc * 64 + n) * 768 + h * 64 + d] = __float2bfloat16(fmaxf(v, 0.f));
    }
}

// ---------------------------------------------------------------------------
extern "C" void kernel_launch(void* const* d_in, const int* in_sizes, int n_in,
                              void* d_out, int out_size, void* d_ws, size_t ws_size,
                              hipStream_t stream) {
    char* ws = (char*)d_ws;
    size_t off = 0;
    int*   flag   = (int*)(ws + off);   off += 16;
    HBF*   xb     = (HBF*)(ws + off);   off += (size_t)4096 * 768 * 2;
    HBF*   Wqkvb  = (HBF*)(ws + off);   off += (size_t)2304 * 768 * 2;
    HBF*   Wprojb = (HBF*)(ws + off);   off += (size_t)768 * 768 * 2;
    HBF*   bprojb = (HBF*)(ws + off);   off += 2048;
    HBF*   QKraw  = (HBF*)(ws + off);   off += (size_t)2 * 24 * 2048 * 64 * 2;
    HBF*   QKn    = (HBF*)(ws + off);   off += (size_t)2 * 24 * 2048 * 64 * 2;
    HBF*   Vb     = (HBF*)(ws + off);   off += (size_t)24 * 2048 * 64 * 2;
    float* P      = (float*)(ws + off); off += (size_t)24 * 16 * 12288 * 4;
    float* M      = (float*)(ws + off); off += (size_t)24 * 12288 * 4;
    float* W      = (float*)(ws + off); off += (size_t)24 * 4096 * 4;
    HBF*   AO     = (HBF*)(ws + off);   off += (size_t)4096 * 768 * 2;
    // total ~69 MB

    HBF* Qn = QKn;
    HBF* Kn = QKn + (size_t)24 * 2048 * 64;

    // 0) dtype detect + canonicalize inputs to bf16
    detect_dtype<<<1, 256, 0, stream>>>((const unsigned int*)d_in[0], flag);
    convert_bf16<<<1024, 256, 0, stream>>>(d_in[0], xb,     4096 * 768,  flag);
    convert_bf16<<<1024, 256, 0, stream>>>(d_in[1], Wqkvb,  2304 * 768,  flag);
    convert_bf16<<<512,  256, 0, stream>>>(d_in[2], Wprojb, 768 * 768,   flag);
    convert_bf16<<<3,    256, 0, stream>>>(d_in[3], bprojb, 768,         flag);

    // 1) qkv = x @ Wqkv^T, scattered directly into head-split Q/K raw + V
    gemm128<false, false, true><<<dim3(32, 18), 256, 0, stream>>>(
        xb, Wqkvb, nullptr, nullptr, QKraw, Vb, 4096, 2304, 768, nullptr);

    // 2) L2-normalize Q,K rows (V untouched)
    normalize_qk<<<3072, 256, 0, stream>>>(QKraw, QKn);

    // 3) Gram partials (no atomics) + tree reduce
    gram_partial<<<dim3(24, 16), 256, 0, stream>>>(Qn, Kn, Vb, P);
    gram_reduce<<<1152, 256, 0, stream>>>(P, M);

    // 4) W combine
    combine_w<<<dim3(24, 8), 256, 0, stream>>>(M, W);

    // 5) relu(V + Kn@W - 0.05) -> [B,N,C] bf16
    epilogue_attn<<<dim3(24, 32), 256, 0, stream>>>(Kn, Vb, W, AO);

    // 6) out = AO @ Wproj^T + bproj, dtype per flag
    gemm128<true, true, false><<<dim3(32, 6), 256, 0, stream>>>(
        AO, Wprojb, bprojb, d_out, nullptr, nullptr, 4096, 768, 768, flag);
}

// Round 5
// 177.432 us; speedup vs baseline: 1.7427x; 1.0874x over previous
//
#include <hip/hip_runtime.h>
#include <hip/hip_bf16.h>

typedef __attribute__((ext_vector_type(8))) __bf16 bf16x8;
typedef __attribute__((ext_vector_type(4))) float f32x4;

#define HBF __hip_bfloat16

// B=2, N=2048, C=768, H=12, D=64
static constexpr float SCALE_C = 0.125f;   // D^-0.5
static constexpr float STEP_C  = 0.1f;
static constexpr float LAMBD_C = 0.5f;

// ---------------------------------------------------------------------------
// Input dtype detection (fp32 vs bf16 inputs). flag=1 -> fp32, 0 -> bf16.
// ---------------------------------------------------------------------------
__device__ __forceinline__ int sane_f(float v) {
    float a = fabsf(v);
    return (a <= 1.0e4f && (a >= 1.0e-6f || v == 0.0f)) ? 1 : 0;   // NaN -> 0
}

__global__ void detect_dtype(const unsigned int* __restrict__ words,
                             int* __restrict__ flag) {
    __shared__ int s32, s16;
    if (threadIdx.x == 0) { s32 = 0; s16 = 0; }
    __syncthreads();
    const unsigned int w = words[threadIdx.x];
    const float f  = __uint_as_float(w);
    const float h0 = __uint_as_float((w & 0xFFFFu) << 16);
    const float h1 = __uint_as_float(w & 0xFFFF0000u);
    atomicAdd(&s32, sane_f(f));
    atomicAdd(&s16, sane_f(h0) + sane_f(h1));
    __syncthreads();
    if (threadIdx.x == 0) flag[0] = (2 * s32 >= s16) ? 1 : 0;
}

// Vectorized canonicalize to bf16: 8 elems/thread/iter, 16B stores.
__global__ __launch_bounds__(256) void convert_bf16v(const void* __restrict__ src,
                                                     HBF* __restrict__ dst, int n8,
                                                     const int* __restrict__ flag) {
    const int f = *flag;
    int i = blockIdx.x * 256 + threadIdx.x;
    const int stride = gridDim.x * 256;
    if (f) {
        const float4* s = (const float4*)src;
        for (; i < n8; i += stride) {
            float4 a = s[2 * i], b = s[2 * i + 1];
            HBF o[8] = {__float2bfloat16(a.x), __float2bfloat16(a.y),
                        __float2bfloat16(a.z), __float2bfloat16(a.w),
                        __float2bfloat16(b.x), __float2bfloat16(b.y),
                        __float2bfloat16(b.z), __float2bfloat16(b.w)};
            ((uint4*)dst)[i] = *(const uint4*)o;
        }
    } else {
        const uint4* s = (const uint4*)src;
        for (; i < n8; i += stride) ((uint4*)dst)[i] = s[i];
    }
}

// ---------------------------------------------------------------------------
// bf16 GEMM, B^T layout: C[m,n] = sum_k A[m,k]*B[n,k] (+bias[n])
// Tile 128 x (NJ*32), 256 thr = 4 waves (2x2), wave = 64 x (NJ*16) via MFMA
// 16x16x32. global_load_lds width-16 staging with XOR chunk swizzle.
// Epilogue: per-wave LDS repack -> dwordx4 coalesced stores.
// SPLITQKV (NJ=4 only): scatter into head-split Q/K raw + V ([bh][n][64]).
// FINAL: out dtype per runtime flag (1->fp32 scalar path, 0->bf16 vector path).
// ---------------------------------------------------------------------------
template <int NJ, bool BIAS, bool FINAL, bool SPLITQKV>
__global__ __launch_bounds__(256) void gemm128(const HBF* __restrict__ A,
                                               const HBF* __restrict__ B,
                                               const HBF* __restrict__ bias,
                                               void* __restrict__ Cout,
                                               HBF* __restrict__ qraw,   // [2][24][2048][64]
                                               HBF* __restrict__ vbuf,   // [24][2048][64]
                                               int M, int N, int K,
                                               const int* __restrict__ flagp) {
    constexpr int TN = NJ * 32;
    __shared__ HBF smem[128 * 64 + TN * 64];
    HBF* As = smem;
    HBF* Bs = smem + 128 * 64;

    int outf32 = 0;
    if (FINAL) outf32 = *flagp;

    const int tid  = threadIdx.x;
    const int wv   = tid >> 6, lane = tid & 63;
    const int m0   = blockIdx.x * 128, n0 = blockIdx.y * TN;
    const int wr = wv >> 1, wc = wv & 1;
    const int l15 = lane & 15, quad = lane >> 4;
    const int srow   = lane >> 3;
    const int schunk = (lane & 7) ^ srow;

    f32x4 acc[4][NJ] = {};

    for (int k0 = 0; k0 < K; k0 += 64) {
#pragma unroll
        for (int d = 0; d < 4; d++) {
            const int region = d * 4 + wv;     // 16 regions x 8 rows (A)
            const int row = region * 8 + srow;
            const HBF* ga = A + (size_t)(m0 + row) * K + k0 + schunk * 8;
            __builtin_amdgcn_global_load_lds((const void*)ga, (void*)(As + region * 512), 16, 0, 0);
        }
#pragma unroll
        for (int d = 0; d < TN / 32; d++) {
            const int region = d * 4 + wv;     // TN/8 regions (B)
            const int row = region * 8 + srow;
            const HBF* gb = B + (size_t)(n0 + row) * K + k0 + schunk * 8;
            __builtin_amdgcn_global_load_lds((const void*)gb, (void*)(Bs + region * 512), 16, 0, 0);
        }
        __syncthreads();

#pragma unroll
        for (int s = 0; s < 2; s++) {
            bf16x8 af[4], bfr[NJ];
#pragma unroll
            for (int i = 0; i < 4; i++) {
                const int row = wr * 64 + i * 16 + l15;
                const int ch = (s * 4 + quad) ^ (row & 7);
                af[i] = *reinterpret_cast<const bf16x8*>(&As[row * 64 + ch * 8]);
            }
#pragma unroll
            for (int j = 0; j < NJ; j++) {
                const int col = wc * (NJ * 16) + j * 16 + l15;
                const int ch = (s * 4 + quad) ^ (col & 7);
                bfr[j] = *reinterpret_cast<const bf16x8*>(&Bs[col * 64 + ch * 8]);
            }
#pragma unroll
            for (int i = 0; i < 4; i++)
#pragma unroll
                for (int j = 0; j < NJ; j++)
                    acc[i][j] = __builtin_amdgcn_mfma_f32_16x16x32_bf16(af[i], bfr[j], acc[i][j], 0, 0, 0);
        }
        __syncthreads();
    }

    // ---- epilogue ----
    float bvals[NJ];
#pragma unroll
    for (int j = 0; j < NJ; j++) {
        bvals[j] = 0.f;
        if (BIAS) bvals[j] = __bfloat162float(bias[n0 + wc * NJ * 16 + j * 16 + l15]);
    }

    if (FINAL && outf32) {   // fp32 output path (rare): scalar stores
#pragma unroll
        for (int i = 0; i < 4; i++)
#pragma unroll
            for (int j = 0; j < NJ; j++) {
                const int col = n0 + wc * NJ * 16 + j * 16 + l15;
#pragma unroll
                for (int r = 0; r < 4; r++) {
                    const int row = m0 + wr * 64 + i * 16 + quad * 4 + r;
                    ((float*)Cout)[(size_t)row * N + col] = acc[i][j][r] + bvals[j];
                }
            }
        return;
    }

    // bf16 vector path: per-wave LDS repack (pad RS keeps banks <=2-way, rows 16B-aligned)
    constexpr int RS = (NJ == 4) ? 72 : 40;    // elements per staged row
    constexpr int CH = NJ * 2;                 // 16B chunks per row
    constexpr int ITERS = 32 * CH / 64;
    HBF* ep = smem + wv * (32 * RS);

#pragma unroll
    for (int ih = 0; ih < 2; ih++) {
        __syncthreads();
#pragma unroll
        for (int ii = 0; ii < 2; ii++) {
            const int i = ih * 2 + ii;
#pragma unroll
            for (int j = 0; j < NJ; j++)
#pragma unroll
                for (int r = 0; r < 4; r++)
                    ep[(ii * 16 + quad * 4 + r) * RS + j * 16 + l15] =
                        __float2bfloat16(acc[i][j][r] + bvals[j]);
        }
        __syncthreads();
        const int rowstart = m0 + wr * 64 + ih * 32;
#pragma unroll
        for (int it = 0; it < ITERS; it++) {
            const int idx = it * 64 + lane;
            const int rl = idx / CH, ch = idx % CH;
            const uint4 val = *(const uint4*)((const char*)ep + rl * (RS * 2) + ch * 16);
            if (SPLITQKV) {
                const int colbase = n0 + wc * 64;            // 64-aligned, single head
                const int tsel = (colbase >= 1536) ? 2 : (colbase >= 768 ? 1 : 0);
                const int h = (colbase - tsel * 768) >> 6;
                HBF* tp = (tsel == 2) ? vbuf : (qraw + (size_t)tsel * (24 * 2048 * 64));
                const int b = rowstart >> 11, n = rowstart & 2047;
                char* dst = (char*)(tp + ((size_t)(b * 12 + h) * 2048 + n) * 64);
                *(uint4*)(dst + rl * 128 + ch * 16) = val;   // contiguous 4KB region
            } else {
                const int grow = rowstart + rl;
                const int col = n0 + wc * NJ * 16 + ch * 8;
                *(uint4*)((HBF*)Cout + (size_t)grow * N + col) = val;
            }
        }
    }
}

// ---------------------------------------------------------------------------
// Gram partials per (head, chunk of 128 rows) with FUSED L2-normalization of
// Q,K rows: Mkv = Kn^T V, Mqv = Qn^T V, Mqq = Qn^T Qn. No atomics.
// ---------------------------------------------------------------------------
__global__ __launch_bounds__(256) void gram_partial(const HBF* __restrict__ Qraw,
                                                    const HBF* __restrict__ Kraw,
                                                    const HBF* __restrict__ Vb,
                                                    float* __restrict__ P) {
    const int bh = blockIdx.x;
    const int cn = blockIdx.y;
    const int t = threadIdx.x;
    __shared__ float Qs[2048], Ks[2048], Vs[2048];
    const int ti = t >> 4, tj = t & 15;

    float akv[4][4] = {}, aqv[4][4] = {}, aqq[4][4] = {};

    for (int it = 0; it < 4; it++) {
        const size_t gbase = ((size_t)bh * 2048 + cn * 128 + it * 32) * 64 + t * 8;
        __syncthreads();
        {
            uint4 rq = *(const uint4*)(Qraw + gbase);
            uint4 rk = *(const uint4*)(Kraw + gbase);
            uint4 rv = *(const uint4*)(Vb + gbase);
            const HBF* hq = (const HBF*)&rq;
            const HBF* hk = (const HBF*)&rk;
            const HBF* hv = (const HBF*)&rv;
            float q[8], k[8];
            float sq = 0.f, sk = 0.f;
#pragma unroll
            for (int i = 0; i < 8; i++) {
                q[i] = __bfloat162float(hq[i]); sq += q[i] * q[i];
                k[i] = __bfloat162float(hk[i]); sk += k[i] * k[i];
            }
#pragma unroll
            for (int off = 1; off <= 4; off <<= 1) {
                sq += __shfl_xor(sq, off, 64);
                sk += __shfl_xor(sk, off, 64);
            }
            const float iq = 1.0f / fmaxf(sqrtf(sq), 1e-12f);
            const float ik = 1.0f / fmaxf(sqrtf(sk), 1e-12f);
#pragma unroll
            for (int i = 0; i < 8; i++) {
                Qs[t * 8 + i] = q[i] * iq;
                Ks[t * 8 + i] = k[i] * ik;
                Vs[t * 8 + i] = __bfloat162float(hv[i]);
            }
        }
        __syncthreads();

#pragma unroll 4
        for (int nn = 0; nn < 32; nn++) {
            float qi[4], ki[4], vj[4], qj[4];
#pragma unroll
            for (int a = 0; a < 4; a++) {
                qi[a] = Qs[nn * 64 + ti + 16 * a];
                ki[a] = Ks[nn * 64 + ti + 16 * a];
                vj[a] = Vs[nn * 64 + tj + 16 * a];
                qj[a] = Qs[nn * 64 + tj + 16 * a];
            }
#pragma unroll
            for (int a = 0; a < 4; a++)
#pragma unroll
                for (int c = 0; c < 4; c++) {
                    akv[a][c] += ki[a] * vj[c];
                    aqv[a][c] += qi[a] * vj[c];
                    aqq[a][c] += qi[a] * qj[c];
                }
        }
    }

    float* Pb = P + ((size_t)bh * 16 + cn) * 12288;
#pragma unroll
    for (int a = 0; a < 4; a++)
#pragma unroll
        for (int c = 0; c < 4; c++) {
            const int i = ti + 16 * a, j = tj + 16 * c;
            Pb[i * 64 + j]        = akv[a][c];
            Pb[4096 + i * 64 + j] = aqv[a][c];
            Pb[8192 + i * 64 + j] = aqq[a][c];
        }
}

// Sum the 16 slabs per head: M[head][3*4096] = sum_s P[head][s][...]
__global__ __launch_bounds__(256) void gram_reduce(const float* __restrict__ P,
                                                   float* __restrict__ M) {
    const int o = blockIdx.x * 256 + threadIdx.x;   // 0..294911
    const int head = o / 12288, e = o % 12288;
    const float* Pb = P + (size_t)head * 16 * 12288 + e;
    float s = 0.f;
#pragma unroll
    for (int k = 0; k < 16; k++) s += Pb[(size_t)k * 12288];
    M[o] = s;
}

// ---------------------------------------------------------------------------
// W = 0.1*s*Mqv - 0.1*s^2 * (Mqq @ Mkv)  per head. grid (24, 8 row-groups).
// ---------------------------------------------------------------------------
__global__ __launch_bounds__(256) void combine_w(const float* __restrict__ M,
                                                 float* __restrict__ W) {
    const int bh = blockIdx.x;
    const int by = blockIdx.y;
    const int t = threadIdx.x;
    __shared__ float Kv[4096];
    __shared__ float Qq8[512];
    const float* Mb = M + (size_t)bh * 12288;
#pragma unroll
    for (int r = 0; r < 16; r++) Kv[t + 256 * r] = Mb[t + 256 * r];
#pragma unroll
    for (int r = 0; r < 2; r++)  Qq8[t + 256 * r] = Mb[8192 + by * 512 + t + 256 * r];
    __syncthreads();

    const int il = t >> 5;
    const int j0 = (t & 31) * 2;
    float s0 = 0.f, s1 = 0.f;
#pragma unroll
    for (int k = 0; k < 64; k++) {
        const float q = Qq8[il * 64 + k];
        const float2 kv = *(const float2*)&Kv[k * 64 + j0];
        s0 += q * kv.x;
        s1 += q * kv.y;
    }
    const int i = by * 8 + il;
    const size_t o = (size_t)bh * 4096 + i * 64 + j0;
    W[o]     = STEP_C * (SCALE_C * Mb[4096 + i * 64 + j0]     - SCALE_C * SCALE_C * s0);
    W[o + 1] = STEP_C * (SCALE_C * Mb[4096 + i * 64 + j0 + 1] - SCALE_C * SCALE_C * s1);
}

// ---------------------------------------------------------------------------
// AO[b, n, h*64+d] = relu(V + (normalize(Kraw[bh,n,:]) @ W[bh])[d] - 0.05), bf16.
// K normalization fused into staging.
// ---------------------------------------------------------------------------
__global__ __launch_bounds__(256) void epilogue_attn(const HBF* __restrict__ Kraw,
                                                     const HBF* __restrict__ Vb,
                                                     const float* __restrict__ W,
                                                     HBF* __restrict__ AO) {
    const int bh = blockIdx.x;
    const int nc = blockIdx.y;
    const int b = bh / 12, h = bh % 12;
    const int t = threadIdx.x;
    __shared__ float Ws[4096];
    __shared__ float Ks[4096];
    const float* Wb = W + (size_t)bh * 4096;
    const size_t kbase = ((size_t)bh * 2048 + nc * 64) * 64;
#pragma unroll
    for (int r = 0; r < 16; r++) Ws[t + 256 * r] = Wb[t + 256 * r];
#pragma unroll
    for (int rr = 0; rr < 2; rr++) {
        uint4 rk = *(const uint4*)(Kraw + kbase + rr * 2048 + t * 8);
        const HBF* hk = (const HBF*)&rk;
        float k[8];
        float sk = 0.f;
#pragma unroll
        for (int i = 0; i < 8; i++) { k[i] = __bfloat162float(hk[i]); sk += k[i] * k[i]; }
#pragma unroll
        for (int off = 1; off <= 4; off <<= 1) sk += __shfl_xor(sk, off, 64);
        const float ik = 1.0f / fmaxf(sqrtf(sk), 1e-12f);
#pragma unroll
        for (int i = 0; i < 8; i++) Ks[rr * 2048 + t * 8 + i] = k[i] * ik;
    }
    __syncthreads();

    const int nl = t >> 6, d = t & 63;
    float wcol[64];
#pragma unroll
    for (int k = 0; k < 64; k++) wcol[k] = Ws[k * 64 + d];

#pragma unroll
    for (int rep = 0; rep < 16; rep++) {
        const int n = rep * 4 + nl;
        float acc = 0.f;
#pragma unroll
        for (int k4 = 0; k4 < 16; k4++) {
            const float4 kv = *(const float4*)&Ks[n * 64 + k4 * 4];
            acc += kv.x * wcol[k4 * 4] + kv.y * wcol[k4 * 4 + 1]
                 + kv.z * wcol[k4 * 4 + 2] + kv.w * wcol[k4 * 4 + 3];
        }
        float v = __bfloat162float(Vb[kbase + (size_t)n * 64 + d]) + acc - (STEP_C * LAMBD_C);
        AO[((size_t)b * 2048 + nc * 64 + n) * 768 + h * 64 + d] = __float2bfloat16(fmaxf(v, 0.f));
    }
}

// ---------------------------------------------------------------------------
extern "C" void kernel_launch(void* const* d_in, const int* in_sizes, int n_in,
                              void* d_out, int out_size, void* d_ws, size_t ws_size,
                              hipStream_t stream) {
    char* ws = (char*)d_ws;
    size_t off = 0;
    int*   flag   = (int*)(ws + off);   off += 16;
    HBF*   xb     = (HBF*)(ws + off);   off += (size_t)4096 * 768 * 2;
    HBF*   Wqkvb  = (HBF*)(ws + off);   off += (size_t)2304 * 768 * 2;
    HBF*   Wprojb = (HBF*)(ws + off);   off += (size_t)768 * 768 * 2;
    HBF*   bprojb = (HBF*)(ws + off);   off += 2048;
    HBF*   QKraw  = (HBF*)(ws + off);   off += (size_t)2 * 24 * 2048 * 64 * 2;
    HBF*   Vb     = (HBF*)(ws + off);   off += (size_t)24 * 2048 * 64 * 2;
    float* P      = (float*)(ws + off); off += (size_t)24 * 16 * 12288 * 4;
    float* M      = (float*)(ws + off); off += (size_t)24 * 12288 * 4;
    float* W      = (float*)(ws + off); off += (size_t)24 * 4096 * 4;
    HBF*   AO     = (HBF*)(ws + off);   off += (size_t)4096 * 768 * 2;
    // total ~57 MB

    HBF* Qraw = QKraw;
    HBF* Kraw = QKraw + (size_t)24 * 2048 * 64;

    // 0) dtype detect + canonicalize inputs to bf16 (vectorized)
    detect_dtype<<<1, 256, 0, stream>>>((const unsigned int*)d_in[0], flag);
    convert_bf16v<<<1536, 256, 0, stream>>>(d_in[0], xb,     (4096 * 768) / 8, flag);
    convert_bf16v<<<864,  256, 0, stream>>>(d_in[1], Wqkvb,  (2304 * 768) / 8, flag);
    convert_bf16v<<<288,  256, 0, stream>>>(d_in[2], Wprojb, (768 * 768) / 8,  flag);
    convert_bf16v<<<1,    256, 0, stream>>>(d_in[3], bprojb, 768 / 8,          flag);

    // 1) qkv = x @ Wqkv^T, scattered directly into head-split Q/K raw + V
    gemm128<4, false, false, true><<<dim3(32, 18), 256, 0, stream>>>(
        xb, Wqkvb, nullptr, nullptr, QKraw, Vb, 4096, 2304, 768, nullptr);

    // 2) Gram partials (normalization fused, no atomics) + tree reduce
    gram_partial<<<dim3(24, 16), 256, 0, stream>>>(Qraw, Kraw, Vb, P);
    gram_reduce<<<1152, 256, 0, stream>>>(P, M);

    // 3) W combine
    combine_w<<<dim3(24, 8), 256, 0, stream>>>(M, W);

    // 4) relu(V + Kn@W - 0.05) -> [B,N,C] bf16 (K-normalization fused)
    epilogue_attn<<<dim3(24, 32), 256, 0, stream>>>(Kraw, Vb, W, AO);

    // 5) out = AO @ Wproj^T + bproj; 128x64 tiles -> 384 blocks (1.5/CU)
    gemm128<2, true, true, false><<<dim3(32, 12), 256, 0, stream>>>(
        AO, Wprojb, bprojb, d_out, nullptr, nullptr, 4096, 768, 768, flag);
}

// Round 6
// 155.928 us; speedup vs baseline: 1.9830x; 1.1379x over previous
//
#include <hip/hip_runtime.h>
#include <hip/hip_bf16.h>

typedef __attribute__((ext_vector_type(8))) __bf16 bf16x8;
typedef __attribute__((ext_vector_type(4))) float f32x4;

#define HBF __hip_bfloat16

// B=2, N=2048, C=768, H=12, D=64
static constexpr float SCALE_C = 0.125f;   // D^-0.5
static constexpr float STEP_C  = 0.1f;
static constexpr float LAMBD_C = 0.5f;

__device__ __forceinline__ int sane_f(float v) {
    float a = fabsf(v);
    return (a <= 1.0e4f && (a >= 1.0e-6f || v == 0.0f)) ? 1 : 0;   // NaN -> 0
}

// ---------------------------------------------------------------------------
// Fused dtype-detect + canonicalize ALL inputs to bf16 in ONE launch.
// Every block reads x's first 64 words and derives the same flag
// (deterministic data). Block 0 publishes it for the final GEMM.
// ---------------------------------------------------------------------------
__global__ __launch_bounds__(256) void convert_all(const void* __restrict__ x,
                                                   const void* __restrict__ wqkv,
                                                   const void* __restrict__ wproj,
                                                   const void* __restrict__ bproj,
                                                   HBF* __restrict__ xb,
                                                   HBF* __restrict__ wqkvb,
                                                   HBF* __restrict__ wprojb,
                                                   HBF* __restrict__ bprojb,
                                                   int* __restrict__ flag) {
    const int t = threadIdx.x, lane = t & 63;
    const unsigned int w = ((const unsigned int*)x)[lane];
    const float f  = __uint_as_float(w);
    const float h0 = __uint_as_float((w & 0xFFFFu) << 16);
    const float h1 = __uint_as_float(w & 0xFFFF0000u);
    int s32 = sane_f(f);
    int s16 = sane_f(h0) + sane_f(h1);
#pragma unroll
    for (int off = 32; off >= 1; off >>= 1) {
        s32 += __shfl_xor(s32, off, 64);
        s16 += __shfl_xor(s16, off, 64);
    }
    const int isf32 = (2 * s32 >= s16) ? 1 : 0;
    if (blockIdx.x == 0 && t == 0) flag[0] = isf32;

    // segment table, in units of 8 elements
    constexpr int C0 = (4096 * 768) / 8;           // x
    constexpr int C1 = C0 + (2304 * 768) / 8;      // +Wqkv
    constexpr int C2 = C1 + (768 * 768) / 8;       // +Wproj
    constexpr int C3 = C2 + 768 / 8;               // +bproj

    int i = blockIdx.x * 256 + t;
    const int stride = gridDim.x * 256;
    for (; i < C3; i += stride) {
        const void* src; HBF* dst; int e;
        if (i < C0)      { src = x;     dst = xb;     e = i; }
        else if (i < C1) { src = wqkv;  dst = wqkvb;  e = i - C0; }
        else if (i < C2) { src = wproj; dst = wprojb; e = i - C1; }
        else             { src = bproj; dst = bprojb; e = i - C2; }
        if (isf32) {
            const float4* s = (const float4*)src;
            float4 a = s[2 * e], b = s[2 * e + 1];
            HBF o[8] = {__float2bfloat16(a.x), __float2bfloat16(a.y),
                        __float2bfloat16(a.z), __float2bfloat16(a.w),
                        __float2bfloat16(b.x), __float2bfloat16(b.y),
                        __float2bfloat16(b.z), __float2bfloat16(b.w)};
            ((uint4*)dst)[e] = *(const uint4*)o;
        } else {
            ((uint4*)dst)[e] = ((const uint4*)src)[e];
        }
    }
}

// ---------------------------------------------------------------------------
// bf16 GEMM, B^T layout: C[m,n] = sum_k A[m,k]*B[n,k] (+bias[n])
// Tile 128 x (NJ*32), 256 thr = 4 waves (2x2), MFMA 16x16x32.
// global_load_lds width-16 staging with XOR chunk swizzle.
// Epilogue: per-wave LDS repack -> dwordx4 coalesced stores.
// SPLITQKV (NJ=4): scatter into head-split Q/K raw + V ([bh][n][64]).
// FINAL: out dtype per runtime flag (1->fp32 scalar path, 0->bf16 vector).
// ---------------------------------------------------------------------------
template <int NJ, bool BIAS, bool FINAL, bool SPLITQKV>
__global__ __launch_bounds__(256) void gemm128(const HBF* __restrict__ A,
                                               const HBF* __restrict__ B,
                                               const HBF* __restrict__ bias,
                                               void* __restrict__ Cout,
                                               HBF* __restrict__ qraw,   // [2][24][2048][64]
                                               HBF* __restrict__ vbuf,   // [24][2048][64]
                                               int M, int N, int K,
                                               const int* __restrict__ flagp) {
    constexpr int TN = NJ * 32;
    __shared__ HBF smem[128 * 64 + TN * 64];
    HBF* As = smem;
    HBF* Bs = smem + 128 * 64;

    int outf32 = 0;
    if (FINAL) outf32 = *flagp;

    const int tid  = threadIdx.x;
    const int wv   = tid >> 6, lane = tid & 63;
    const int m0   = blockIdx.x * 128, n0 = blockIdx.y * TN;
    const int wr = wv >> 1, wc = wv & 1;
    const int l15 = lane & 15, quad = lane >> 4;
    const int srow   = lane >> 3;
    const int schunk = (lane & 7) ^ srow;

    f32x4 acc[4][NJ] = {};

    for (int k0 = 0; k0 < K; k0 += 64) {
#pragma unroll
        for (int d = 0; d < 4; d++) {
            const int region = d * 4 + wv;
            const int row = region * 8 + srow;
            const HBF* ga = A + (size_t)(m0 + row) * K + k0 + schunk * 8;
            __builtin_amdgcn_global_load_lds((const void*)ga, (void*)(As + region * 512), 16, 0, 0);
        }
#pragma unroll
        for (int d = 0; d < TN / 32; d++) {
            const int region = d * 4 + wv;
            const int row = region * 8 + srow;
            const HBF* gb = B + (size_t)(n0 + row) * K + k0 + schunk * 8;
            __builtin_amdgcn_global_load_lds((const void*)gb, (void*)(Bs + region * 512), 16, 0, 0);
        }
        __syncthreads();

#pragma unroll
        for (int s = 0; s < 2; s++) {
            bf16x8 af[4], bfr[NJ];
#pragma unroll
            for (int i = 0; i < 4; i++) {
                const int row = wr * 64 + i * 16 + l15;
                const int ch = (s * 4 + quad) ^ (row & 7);
                af[i] = *reinterpret_cast<const bf16x8*>(&As[row * 64 + ch * 8]);
            }
#pragma unroll
            for (int j = 0; j < NJ; j++) {
                const int col = wc * (NJ * 16) + j * 16 + l15;
                const int ch = (s * 4 + quad) ^ (col & 7);
                bfr[j] = *reinterpret_cast<const bf16x8*>(&Bs[col * 64 + ch * 8]);
            }
#pragma unroll
            for (int i = 0; i < 4; i++)
#pragma unroll
                for (int j = 0; j < NJ; j++)
                    acc[i][j] = __builtin_amdgcn_mfma_f32_16x16x32_bf16(af[i], bfr[j], acc[i][j], 0, 0, 0);
        }
        __syncthreads();
    }

    float bvals[NJ];
#pragma unroll
    for (int j = 0; j < NJ; j++) {
        bvals[j] = 0.f;
        if (BIAS) bvals[j] = __bfloat162float(bias[n0 + wc * NJ * 16 + j * 16 + l15]);
    }

    if (FINAL && outf32) {
#pragma unroll
        for (int i = 0; i < 4; i++)
#pragma unroll
            for (int j = 0; j < NJ; j++) {
                const int col = n0 + wc * NJ * 16 + j * 16 + l15;
#pragma unroll
                for (int r = 0; r < 4; r++) {
                    const int row = m0 + wr * 64 + i * 16 + quad * 4 + r;
                    ((float*)Cout)[(size_t)row * N + col] = acc[i][j][r] + bvals[j];
                }
            }
        return;
    }

    constexpr int RS = (NJ == 4) ? 72 : 40;
    constexpr int CH = NJ * 2;
    constexpr int ITERS = 32 * CH / 64;
    HBF* ep = smem + wv * (32 * RS);

#pragma unroll
    for (int ih = 0; ih < 2; ih++) {
        __syncthreads();
#pragma unroll
        for (int ii = 0; ii < 2; ii++) {
            const int i = ih * 2 + ii;
#pragma unroll
            for (int j = 0; j < NJ; j++)
#pragma unroll
                for (int r = 0; r < 4; r++)
                    ep[(ii * 16 + quad * 4 + r) * RS + j * 16 + l15] =
                        __float2bfloat16(acc[i][j][r] + bvals[j]);
        }
        __syncthreads();
        const int rowstart = m0 + wr * 64 + ih * 32;
#pragma unroll
        for (int it = 0; it < ITERS; it++) {
            const int idx = it * 64 + lane;
            const int rl = idx / CH, ch = idx % CH;
            const uint4 val = *(const uint4*)((const char*)ep + rl * (RS * 2) + ch * 16);
            if (SPLITQKV) {
                const int colbase = n0 + wc * 64;
                const int tsel = (colbase >= 1536) ? 2 : (colbase >= 768 ? 1 : 0);
                const int h = (colbase - tsel * 768) >> 6;
                HBF* tp = (tsel == 2) ? vbuf : (qraw + (size_t)tsel * (24 * 2048 * 64));
                const int b = rowstart >> 11, n = rowstart & 2047;
                char* dst = (char*)(tp + ((size_t)(b * 12 + h) * 2048 + n) * 64);
                *(uint4*)(dst + rl * 128 + ch * 16) = val;
            } else {
                const int grow = rowstart + rl;
                const int col = n0 + wc * NJ * 16 + ch * 8;
                *(uint4*)((HBF*)Cout + (size_t)grow * N + col) = val;
            }
        }
    }
}

// ---------------------------------------------------------------------------
// Gram partials per (head, 64-row chunk), fused L2-normalization of Q,K.
// grid (24,32) = 768 blocks. No atomics.
// ---------------------------------------------------------------------------
__global__ __launch_bounds__(256) void gram_partial(const HBF* __restrict__ Qraw,
                                                    const HBF* __restrict__ Kraw,
                                                    const HBF* __restrict__ Vb,
                                                    float* __restrict__ P) {
    const int bh = blockIdx.x;
    const int cn = blockIdx.y;
    const int t = threadIdx.x;
    __shared__ float Qs[2048], Ks[2048], Vs[2048];
    const int ti = t >> 4, tj = t & 15;

    float akv[4][4] = {}, aqv[4][4] = {}, aqq[4][4] = {};

    for (int it = 0; it < 2; it++) {
        const size_t gbase = ((size_t)bh * 2048 + cn * 64 + it * 32) * 64 + t * 8;
        __syncthreads();
        {
            uint4 rq = *(const uint4*)(Qraw + gbase);
            uint4 rk = *(const uint4*)(Kraw + gbase);
            uint4 rv = *(const uint4*)(Vb + gbase);
            const HBF* hq = (const HBF*)&rq;
            const HBF* hk = (const HBF*)&rk;
            const HBF* hv = (const HBF*)&rv;
            float q[8], k[8];
            float sq = 0.f, sk = 0.f;
#pragma unroll
            for (int i = 0; i < 8; i++) {
                q[i] = __bfloat162float(hq[i]); sq += q[i] * q[i];
                k[i] = __bfloat162float(hk[i]); sk += k[i] * k[i];
            }
#pragma unroll
            for (int off = 1; off <= 4; off <<= 1) {
                sq += __shfl_xor(sq, off, 64);
                sk += __shfl_xor(sk, off, 64);
            }
            const float iq = 1.0f / fmaxf(sqrtf(sq), 1e-12f);
            const float ik = 1.0f / fmaxf(sqrtf(sk), 1e-12f);
#pragma unroll
            for (int i = 0; i < 8; i++) {
                Qs[t * 8 + i] = q[i] * iq;
                Ks[t * 8 + i] = k[i] * ik;
                Vs[t * 8 + i] = __bfloat162float(hv[i]);
            }
        }
        __syncthreads();

#pragma unroll 4
        for (int nn = 0; nn < 32; nn++) {
            float qi[4], ki[4], vj[4], qj[4];
#pragma unroll
            for (int a = 0; a < 4; a++) {
                qi[a] = Qs[nn * 64 + ti + 16 * a];
                ki[a] = Ks[nn * 64 + ti + 16 * a];
                vj[a] = Vs[nn * 64 + tj + 16 * a];
                qj[a] = Qs[nn * 64 + tj + 16 * a];
            }
#pragma unroll
            for (int a = 0; a < 4; a++)
#pragma unroll
                for (int c = 0; c < 4; c++) {
                    akv[a][c] += ki[a] * vj[c];
                    aqv[a][c] += qi[a] * vj[c];
                    aqq[a][c] += qi[a] * qj[c];
                }
        }
    }

    float* Pb = P + ((size_t)bh * 32 + cn) * 12288;
#pragma unroll
    for (int a = 0; a < 4; a++)
#pragma unroll
        for (int c = 0; c < 4; c++) {
            const int i = ti + 16 * a, j = tj + 16 * c;
            Pb[i * 64 + j]        = akv[a][c];
            Pb[4096 + i * 64 + j] = aqv[a][c];
            Pb[8192 + i * 64 + j] = aqq[a][c];
        }
}

// Sum the 32 slabs per head: M[head][3*4096]
__global__ __launch_bounds__(256) void gram_reduce(const float* __restrict__ P,
                                                   float* __restrict__ M) {
    const int o = blockIdx.x * 256 + threadIdx.x;   // 0..294911
    const int head = o / 12288, e = o % 12288;
    const float* Pb = P + (size_t)head * 32 * 12288 + e;
    float s = 0.f;
#pragma unroll
    for (int k = 0; k < 32; k++) s += Pb[(size_t)k * 12288];
    M[o] = s;
}

// ---------------------------------------------------------------------------
// W = 0.1*s*Mqv - 0.1*s^2 * (Mqq @ Mkv); emit TRANSPOSED bf16 Wt[d][k].
// ---------------------------------------------------------------------------
__global__ __launch_bounds__(256) void combine_w(const float* __restrict__ M,
                                                 HBF* __restrict__ Wt) {
    const int bh = blockIdx.x;
    const int by = blockIdx.y;
    const int t = threadIdx.x;
    __shared__ float Kv[4096];
    __shared__ float Qq8[512];
    const float* Mb = M + (size_t)bh * 12288;
#pragma unroll
    for (int r = 0; r < 16; r++) Kv[t + 256 * r] = Mb[t + 256 * r];
#pragma unroll
    for (int r = 0; r < 2; r++)  Qq8[t + 256 * r] = Mb[8192 + by * 512 + t + 256 * r];
    __syncthreads();

    const int il = t >> 5;
    const int j0 = (t & 31) * 2;
    float s0 = 0.f, s1 = 0.f;
#pragma unroll
    for (int k = 0; k < 64; k++) {
        const float q = Qq8[il * 64 + k];
        const float2 kv = *(const float2*)&Kv[k * 64 + j0];
        s0 += q * kv.x;
        s1 += q * kv.y;
    }
    const int i = by * 8 + il;   // k-row of W
    const float w0 = STEP_C * (SCALE_C * Mb[4096 + i * 64 + j0]     - SCALE_C * SCALE_C * s0);
    const float w1 = STEP_C * (SCALE_C * Mb[4096 + i * 64 + j0 + 1] - SCALE_C * SCALE_C * s1);
    Wt[(size_t)bh * 4096 + j0 * 64 + i]       = __float2bfloat16(w0);
    Wt[(size_t)bh * 4096 + (j0 + 1) * 64 + i] = __float2bfloat16(w1);
}

// ---------------------------------------------------------------------------
// MFMA epilogue: AO[b,n,h*64+d] = relu(V + (Kn @ W)[n][d] - 0.05), bf16.
// Per block: 128-row chunk; P = Kn(128x64) @ W(64x64) via 16 MFMA/wave.
// LDS: phase1 Kn(16KB swizzled)+Wt(8KB swizzled); phase2 P fp32 (34KB, overlaid)
// ---------------------------------------------------------------------------
__global__ __launch_bounds__(256) void epilogue_attn(const HBF* __restrict__ Kraw,
                                                     const HBF* __restrict__ Vb,
                                                     const HBF* __restrict__ Wt,
                                                     HBF* __restrict__ AO) {
    __shared__ char smem[34816];
    HBF* Ks  = (HBF*)smem;            // [128][64] swizzled
    HBF* Wts = Ks + 128 * 64;         // [64][64]  swizzled
    float* Ps = (float*)smem;         // phase 2: 4 waves x [32][68]

    const int bh = blockIdx.x, cn = blockIdx.y;
    const int b = bh / 12, h = bh % 12;
    const int t = threadIdx.x, wv = t >> 6, lane = t & 63;
    const int l15 = lane & 15, quad = lane >> 4;
    const size_t kbase = ((size_t)bh * 2048 + cn * 128) * 64;
    const int sub = t & 7;

    // stage normalized Kn -> bf16, XOR-swizzled
#pragma unroll
    for (int rr = 0; rr < 4; rr++) {
        const int row = rr * 32 + (t >> 3);
        uint4 rk = *(const uint4*)(Kraw + kbase + (size_t)row * 64 + sub * 8);
        const HBF* hk = (const HBF*)&rk;
        float k[8]; float sk = 0.f;
#pragma unroll
        for (int i = 0; i < 8; i++) { k[i] = __bfloat162float(hk[i]); sk += k[i] * k[i]; }
#pragma unroll
        for (int off = 1; off <= 4; off <<= 1) sk += __shfl_xor(sk, off, 64);
        const float ik = 1.0f / fmaxf(sqrtf(sk), 1e-12f);
        HBF o[8];
#pragma unroll
        for (int i = 0; i < 8; i++) o[i] = __float2bfloat16(k[i] * ik);
        const int ch = sub ^ (row & 7);
        *(uint4*)(Ks + row * 64 + ch * 8) = *(const uint4*)o;
    }
    // stage Wt (bf16), same swizzle
#pragma unroll
    for (int rr = 0; rr < 2; rr++) {
        const int d = rr * 32 + (t >> 3);
        uint4 v = *(const uint4*)(Wt + (size_t)bh * 4096 + d * 64 + sub * 8);
        const int ch = sub ^ (d & 7);
        *(uint4*)(Wts + d * 64 + ch * 8) = v;
    }
    __syncthreads();

    f32x4 acc[2][4] = {};
#pragma unroll
    for (int s = 0; s < 2; s++) {
        bf16x8 af[2], bfr[4];
#pragma unroll
        for (int i = 0; i < 2; i++) {
            const int row = wv * 32 + i * 16 + l15;
            const int ch = (s * 4 + quad) ^ (row & 7);
            af[i] = *reinterpret_cast<const bf16x8*>(&Ks[row * 64 + ch * 8]);
        }
#pragma unroll
        for (int j = 0; j < 4; j++) {
            const int d = j * 16 + l15;
            const int ch = (s * 4 + quad) ^ (d & 7);
            bfr[j] = *reinterpret_cast<const bf16x8*>(&Wts[d * 64 + ch * 8]);
        }
#pragma unroll
        for (int i = 0; i < 2; i++)
#pragma unroll
            for (int j = 0; j < 4; j++)
                acc[i][j] = __builtin_amdgcn_mfma_f32_16x16x32_bf16(af[i], bfr[j], acc[i][j], 0, 0, 0);
    }
    __syncthreads();   // Ks/Wts dead; reuse LDS for P

    float* Pw = Ps + wv * (32 * 68);
#pragma unroll
    for (int i = 0; i < 2; i++)
#pragma unroll
        for (int j = 0; j < 4; j++)
#pragma unroll
            for (int r = 0; r < 4; r++)
                Pw[(i * 16 + quad * 4 + r) * 68 + j * 16 + l15] = acc[i][j][r];
    __syncthreads();

#pragma unroll
    for (int rr = 0; rr < 4; rr++) {
        const int row = rr * 32 + (t >> 3);      // block-local 0..127
        const float* prow = Ps + (row >> 5) * (32 * 68) + (row & 31) * 68 + sub * 8;
        const float4 p0 = *(const float4*)prow;
        const float4 p1 = *(const float4*)(prow + 4);
        uint4 rv = *(const uint4*)(Vb + kbase + (size_t)row * 64 + sub * 8);
        const HBF* hv = (const HBF*)&rv;
        const float pv[8] = {p0.x, p0.y, p0.z, p0.w, p1.x, p1.y, p1.z, p1.w};
        HBF o[8];
#pragma unroll
        for (int i = 0; i < 8; i++)
            o[i] = __float2bfloat16(fmaxf(__bfloat162float(hv[i]) + pv[i] - (STEP_C * LAMBD_C), 0.f));
        const int n = cn * 128 + row;
        *(uint4*)(AO + ((size_t)b * 2048 + n) * 768 + h * 64 + sub * 8) = *(const uint4*)o;
    }
}

// ---------------------------------------------------------------------------
extern "C" void kernel_launch(void* const* d_in, const int* in_sizes, int n_in,
                              void* d_out, int out_size, void* d_ws, size_t ws_size,
                              hipStream_t stream) {
    char* ws = (char*)d_ws;
    size_t off = 0;
    int*   flag   = (int*)(ws + off);   off += 16;
    HBF*   xb     = (HBF*)(ws + off);   off += (size_t)4096 * 768 * 2;
    HBF*   Wqkvb  = (HBF*)(ws + off);   off += (size_t)2304 * 768 * 2;
    HBF*   Wprojb = (HBF*)(ws + off);   off += (size_t)768 * 768 * 2;
    HBF*   bprojb = (HBF*)(ws + off);   off += 2048;
    HBF*   QKraw  = (HBF*)(ws + off);   off += (size_t)2 * 24 * 2048 * 64 * 2;
    HBF*   Vb     = (HBF*)(ws + off);   off += (size_t)24 * 2048 * 64 * 2;
    float* P      = (float*)(ws + off); off += (size_t)24 * 32 * 12288 * 4;
    float* M      = (float*)(ws + off); off += (size_t)24 * 12288 * 4;
    HBF*   Wt     = (HBF*)(ws + off);   off += (size_t)24 * 4096 * 2;
    HBF*   AO     = (HBF*)(ws + off);   off += (size_t)4096 * 768 * 2;
    // total ~76 MB

    HBF* Qraw = QKraw;
    HBF* Kraw = QKraw + (size_t)24 * 2048 * 64;

    // 0) one fused dtype-detect + convert pass
    convert_all<<<2048, 256, 0, stream>>>(d_in[0], d_in[1], d_in[2], d_in[3],
                                          xb, Wqkvb, Wprojb, bprojb, flag);

    // 1) qkv = x @ Wqkv^T, scattered into head-split Q/K raw + V
    gemm128<4, false, false, true><<<dim3(32, 18), 256, 0, stream>>>(
        xb, Wqkvb, nullptr, nullptr, QKraw, Vb, 4096, 2304, 768, nullptr);

    // 2) Gram partials (normalization fused) + tree reduce
    gram_partial<<<dim3(24, 32), 256, 0, stream>>>(Qraw, Kraw, Vb, P);
    gram_reduce<<<1152, 256, 0, stream>>>(P, M);

    // 3) W combine -> transposed bf16 Wt
    combine_w<<<dim3(24, 8), 256, 0, stream>>>(M, Wt);

    // 4) MFMA epilogue: relu(V + Kn@W - 0.05) -> [B,N,C] bf16
    epilogue_attn<<<dim3(24, 16), 256, 0, stream>>>(Kraw, Vb, Wt, AO);

    // 5) out = AO @ Wproj^T + bproj
    gemm128<2, true, true, false><<<dim3(32, 12), 256, 0, stream>>>(
        AO, Wprojb, bprojb, d_out, nullptr, nullptr, 4096, 768, 768, flag);
}

// Round 7
// 153.457 us; speedup vs baseline: 2.0149x; 1.0161x over previous
//
#include <hip/hip_runtime.h>
#include <hip/hip_bf16.h>

typedef __attribute__((ext_vector_type(8))) __bf16 bf16x8;
typedef __attribute__((ext_vector_type(4))) float f32x4;

#define HBF __hip_bfloat16

// B=2, N=2048, C=768, H=12, D=64
static constexpr float SCALE_C = 0.125f;   // D^-0.5
static constexpr float STEP_C  = 0.1f;
static constexpr float LAMBD_C = 0.5f;

__device__ __forceinline__ int sane_f(float v) {
    float a = fabsf(v);
    return (a <= 1.0e4f && (a >= 1.0e-6f || v == 0.0f)) ? 1 : 0;   // NaN -> 0
}

// ---------------------------------------------------------------------------
// Fused dtype-detect + canonicalize ALL inputs to bf16 in ONE launch.
// ---------------------------------------------------------------------------
__global__ __launch_bounds__(256) void convert_all(const void* __restrict__ x,
                                                   const void* __restrict__ wqkv,
                                                   const void* __restrict__ wproj,
                                                   const void* __restrict__ bproj,
                                                   HBF* __restrict__ xb,
                                                   HBF* __restrict__ wqkvb,
                                                   HBF* __restrict__ wprojb,
                                                   HBF* __restrict__ bprojb,
                                                   int* __restrict__ flag) {
    const int t = threadIdx.x, lane = t & 63;
    const unsigned int w = ((const unsigned int*)x)[lane];
    const float f  = __uint_as_float(w);
    const float h0 = __uint_as_float((w & 0xFFFFu) << 16);
    const float h1 = __uint_as_float(w & 0xFFFF0000u);
    int s32 = sane_f(f);
    int s16 = sane_f(h0) + sane_f(h1);
#pragma unroll
    for (int off = 32; off >= 1; off >>= 1) {
        s32 += __shfl_xor(s32, off, 64);
        s16 += __shfl_xor(s16, off, 64);
    }
    const int isf32 = (2 * s32 >= s16) ? 1 : 0;
    if (blockIdx.x == 0 && t == 0) flag[0] = isf32;

    constexpr int C0 = (4096 * 768) / 8;
    constexpr int C1 = C0 + (2304 * 768) / 8;
    constexpr int C2 = C1 + (768 * 768) / 8;
    constexpr int C3 = C2 + 768 / 8;

    int i = blockIdx.x * 256 + t;
    const int stride = gridDim.x * 256;
    for (; i < C3; i += stride) {
        const void* src; HBF* dst; int e;
        if (i < C0)      { src = x;     dst = xb;     e = i; }
        else if (i < C1) { src = wqkv;  dst = wqkvb;  e = i - C0; }
        else if (i < C2) { src = wproj; dst = wprojb; e = i - C1; }
        else             { src = bproj; dst = bprojb; e = i - C2; }
        if (isf32) {
            const float4* s = (const float4*)src;
            float4 a = s[2 * e], b = s[2 * e + 1];
            HBF o[8] = {__float2bfloat16(a.x), __float2bfloat16(a.y),
                        __float2bfloat16(a.z), __float2bfloat16(a.w),
                        __float2bfloat16(b.x), __float2bfloat16(b.y),
                        __float2bfloat16(b.z), __float2bfloat16(b.w)};
            ((uint4*)dst)[e] = *(const uint4*)o;
        } else {
            ((uint4*)dst)[e] = ((const uint4*)src)[e];
        }
    }
}

// ---------------------------------------------------------------------------
// bf16 GEMM, B^T layout: C[m,n] = sum_k A[m,k]*B[n,k] (+bias[n])
// Tile 128 x (NJ*32), 256 thr = 4 waves (2x2), MFMA 16x16x32.
// global_load_lds width-16 staging with XOR chunk swizzle.
// SPLITQKV (NJ=4): fused per-row L2-norm of Q/K (fp32, in-register), writes:
//   Kn natural [bh][n][64] (normalized), V natural [bh][n][64],
//   QKVt transposed [3][bh][64][2048] (Q,K normalized; V plain).
// FINAL: out dtype per runtime flag (1->fp32 scalar path, 0->bf16 vector).
// ---------------------------------------------------------------------------
template <int NJ, bool BIAS, bool FINAL, bool SPLITQKV>
__global__ __launch_bounds__(256) void gemm128(const HBF* __restrict__ A,
                                               const HBF* __restrict__ B,
                                               const HBF* __restrict__ bias,
                                               void* __restrict__ Cout,
                                               HBF* __restrict__ knat,
                                               HBF* __restrict__ vnat,
                                               HBF* __restrict__ tbuf,
                                               int M, int N, int K,
                                               const int* __restrict__ flagp) {
    constexpr int TN = NJ * 32;
    __shared__ HBF smem[128 * 64 + TN * 64];
    HBF* As = smem;
    HBF* Bs = smem + 128 * 64;

    int outf32 = 0;
    if (FINAL) outf32 = *flagp;

    const int tid  = threadIdx.x;
    const int wv   = tid >> 6, lane = tid & 63;
    const int m0   = blockIdx.x * 128, n0 = blockIdx.y * TN;
    const int wr = wv >> 1, wc = wv & 1;
    const int l15 = lane & 15, quad = lane >> 4;
    const int srow   = lane >> 3;
    const int schunk = (lane & 7) ^ srow;

    f32x4 acc[4][NJ] = {};

    for (int k0 = 0; k0 < K; k0 += 64) {
#pragma unroll
        for (int d = 0; d < 4; d++) {
            const int region = d * 4 + wv;
            const int row = region * 8 + srow;
            const HBF* ga = A + (size_t)(m0 + row) * K + k0 + schunk * 8;
            __builtin_amdgcn_global_load_lds((const void*)ga, (void*)(As + region * 512), 16, 0, 0);
        }
#pragma unroll
        for (int d = 0; d < TN / 32; d++) {
            const int region = d * 4 + wv;
            const int row = region * 8 + srow;
            const HBF* gb = B + (size_t)(n0 + row) * K + k0 + schunk * 8;
            __builtin_amdgcn_global_load_lds((const void*)gb, (void*)(Bs + region * 512), 16, 0, 0);
        }
        __syncthreads();

#pragma unroll
        for (int s = 0; s < 2; s++) {
            bf16x8 af[4], bfr[NJ];
#pragma unroll
            for (int i = 0; i < 4; i++) {
                const int row = wr * 64 + i * 16 + l15;
                const int ch = (s * 4 + quad) ^ (row & 7);
                af[i] = *reinterpret_cast<const bf16x8*>(&As[row * 64 + ch * 8]);
            }
#pragma unroll
            for (int j = 0; j < NJ; j++) {
                const int col = wc * (NJ * 16) + j * 16 + l15;
                const int ch = (s * 4 + quad) ^ (col & 7);
                bfr[j] = *reinterpret_cast<const bf16x8*>(&Bs[col * 64 + ch * 8]);
            }
#pragma unroll
            for (int i = 0; i < 4; i++)
#pragma unroll
                for (int j = 0; j < NJ; j++)
                    acc[i][j] = __builtin_amdgcn_mfma_f32_16x16x32_bf16(af[i], bfr[j], acc[i][j], 0, 0, 0);
        }
        __syncthreads();   // last iter: all frag reads done before epilogue reuses smem
    }

    if (SPLITQKV) {
        // ---- fused split epilogue ----
        HBF* wpriv = smem + wv * 4096;   // 8 KB wave-private scratch
        const int colbase = n0 + wc * 64;
        const int tsel = (colbase >= 1536) ? 2 : (colbase >= 768 ? 1 : 0);
        const int h = (colbase - tsel * 768) >> 6;

        // L2-normalize rows (Q, K) in fp32
        if (tsel < 2) {
#pragma unroll
            for (int i = 0; i < 4; i++)
#pragma unroll
                for (int r = 0; r < 4; r++) {
                    float ss = acc[i][0][r] * acc[i][0][r] + acc[i][1][r] * acc[i][1][r]
                             + acc[i][2][r] * acc[i][2][r] + acc[i][3][r] * acc[i][3][r];
#pragma unroll
                    for (int off = 1; off <= 8; off <<= 1) ss += __shfl_xor(ss, off, 64);
                    const float inv = 1.0f / fmaxf(sqrtf(ss), 1e-12f);
#pragma unroll
                    for (int j = 0; j < 4; j++) acc[i][j][r] *= inv;
                }
        }

#pragma unroll
        for (int ih = 0; ih < 2; ih++) {
            const int rowstart = m0 + wr * 64 + ih * 32;
            const int b = rowstart >> 11, nloc = rowstart & 2047;
            const size_t bh = (size_t)(b * 12 + h);

            if (tsel != 0) {   // natural store (K normalized, V plain); Q natural unused
                HBF* ep = wpriv;   // [32][72]
#pragma unroll
                for (int ii = 0; ii < 2; ii++) {
                    const int i = ih * 2 + ii;
#pragma unroll
                    for (int j = 0; j < 4; j++)
#pragma unroll
                        for (int r = 0; r < 4; r++)
                            ep[(ii * 16 + quad * 4 + r) * 72 + j * 16 + l15] =
                                __float2bfloat16(acc[i][j][r]);
                }
                HBF* dst0 = ((tsel == 2) ? vnat : knat) + (bh * 2048 + nloc) * 64;
#pragma unroll
                for (int it = 0; it < 4; it++) {
                    const int idx = it * 64 + lane;
                    const int rl = idx >> 3, ch = idx & 7;
                    const uint4 val = *(const uint4*)((const char*)ep + rl * 144 + ch * 16);
                    *(uint4*)((char*)dst0 + rl * 128 + ch * 16) = val;
                }
            }
            {   // transposed store -> QKVt[tsel][bh][d][n]
                HBF* epT = wpriv;  // [64][34]  (reuses region; per-wave DS ops are in-order)
#pragma unroll
                for (int ii = 0; ii < 2; ii++) {
                    const int i = ih * 2 + ii;
#pragma unroll
                    for (int j = 0; j < 4; j++)
#pragma unroll
                        for (int r = 0; r < 4; r++)
                            epT[(j * 16 + l15) * 34 + ii * 16 + quad * 4 + r] =
                                __float2bfloat16(acc[i][j][r]);
                }
                HBF* tdst = tbuf + (size_t)tsel * (24 * 64 * 2048) + (bh * 64) * 2048 + nloc;
#pragma unroll
                for (int it = 0; it < 4; it++) {
                    const int idx = it * 64 + lane;
                    const int d = idx >> 2, c = idx & 3;
                    const uint4 val = *(const uint4*)(epT + d * 34 + c * 8);
                    *(uint4*)(tdst + (size_t)d * 2048 + c * 8) = val;
                }
            }
        }
        return;
    }

    // ---- plain epilogue ----
    float bvals[NJ];
#pragma unroll
    for (int j = 0; j < NJ; j++) {
        bvals[j] = 0.f;
        if (BIAS) bvals[j] = __bfloat162float(bias[n0 + wc * NJ * 16 + j * 16 + l15]);
    }

    if (FINAL && outf32) {
#pragma unroll
        for (int i = 0; i < 4; i++)
#pragma unroll
            for (int j = 0; j < NJ; j++) {
                const int col = n0 + wc * NJ * 16 + j * 16 + l15;
#pragma unroll
                for (int r = 0; r < 4; r++) {
                    const int row = m0 + wr * 64 + i * 16 + quad * 4 + r;
                    ((float*)Cout)[(size_t)row * N + col] = acc[i][j][r] + bvals[j];
                }
            }
        return;
    }

    constexpr int RS = (NJ == 4) ? 72 : 40;
    constexpr int CH = NJ * 2;
    constexpr int ITERS = 32 * CH / 64;
    HBF* ep = smem + wv * (32 * RS);

#pragma unroll
    for (int ih = 0; ih < 2; ih++) {
#pragma unroll
        for (int ii = 0; ii < 2; ii++) {
            const int i = ih * 2 + ii;
#pragma unroll
            for (int j = 0; j < NJ; j++)
#pragma unroll
                for (int r = 0; r < 4; r++)
                    ep[(ii * 16 + quad * 4 + r) * RS + j * 16 + l15] =
                        __float2bfloat16(acc[i][j][r] + bvals[j]);
        }
        const int rowstart = m0 + wr * 64 + ih * 32;
#pragma unroll
        for (int it = 0; it < ITERS; it++) {
            const int idx = it * 64 + lane;
            const int rl = idx / CH, ch = idx % CH;
            const uint4 val = *(const uint4*)((const char*)ep + rl * (RS * 2) + ch * 16);
            const int grow = rowstart + rl;
            const int col = n0 + wc * NJ * 16 + ch * 8;
            *(uint4*)((HBF*)Cout + (size_t)grow * N + col) = val;
        }
    }
}

// ---------------------------------------------------------------------------
// MFMA Gram partials from transposed tensors. Block = (head, 128-n chunk).
// LDS: KT/QT/VT [64][128] bf16, XOR-16-chunk swizzled, via global_load_lds.
// Wave w computes tile-row w of Mkv, Mqv, Mqq (A-frag reuse). No atomics.
// ---------------------------------------------------------------------------
__global__ __launch_bounds__(256) void gram_mfma(const HBF* __restrict__ QKVt,
                                                 float* __restrict__ P) {
    __shared__ HBF lds[3 * 8192];   // 48 KB
    const int bh = blockIdx.x, cn = blockIdx.y;
    const int t = threadIdx.x, wv = t >> 6, lane = t & 63;
    const int l15 = lane & 15, quad = lane >> 4;
    constexpr size_t S = (size_t)24 * 64 * 2048;
    const HBF* srcs[3] = {QKVt + S, QKVt, QKVt + 2 * S};   // K, Q, V

    const int rowq = lane >> 4;       // 0..3 rows per wave-load
    const int cgb  = lane & 15;       // 16B chunk id
#pragma unroll
    for (int t3 = 0; t3 < 3; t3++) {
        const HBF* base = srcs[t3] + (size_t)bh * 64 * 2048 + cn * 128;
#pragma unroll
        for (int rg = 0; rg < 4; rg++) {
            const int region = rg * 4 + wv;         // 0..15
            const int row = region * 4 + rowq;      // 0..63 (d)
            const int cg = cgb ^ (row & 15);
            __builtin_amdgcn_global_load_lds((const void*)(base + (size_t)row * 2048 + cg * 8),
                                             (void*)(lds + t3 * 8192 + region * 512), 16, 0, 0);
        }
    }
    __syncthreads();

    const HBF* Kt = lds;
    const HBF* Qt = lds + 8192;
    const HBF* Vt = lds + 16384;
    f32x4 aKV[4] = {}, aQV[4] = {}, aQQ[4] = {};
    const int i = wv;   // tile-row of the 64x64 Grams
#pragma unroll
    for (int s = 0; s < 4; s++) {
        const int q = (s * 4 + quad) ^ l15;
        const bf16x8 aK = *(const bf16x8*)(Kt + (i * 16 + l15) * 128 + q * 8);
        const bf16x8 aQ = *(const bf16x8*)(Qt + (i * 16 + l15) * 128 + q * 8);
#pragma unroll
        for (int j = 0; j < 4; j++) {
            const bf16x8 bV = *(const bf16x8*)(Vt + (j * 16 + l15) * 128 + q * 8);
            const bf16x8 bQ = *(const bf16x8*)(Qt + (j * 16 + l15) * 128 + q * 8);
            aKV[j] = __builtin_amdgcn_mfma_f32_16x16x32_bf16(aK, bV, aKV[j], 0, 0, 0);
            aQV[j] = __builtin_amdgcn_mfma_f32_16x16x32_bf16(aQ, bV, aQV[j], 0, 0, 0);
            aQQ[j] = __builtin_amdgcn_mfma_f32_16x16x32_bf16(aQ, bQ, aQQ[j], 0, 0, 0);
        }
    }

    float* Pb = P + ((size_t)bh * 16 + cn) * 12288;
#pragma unroll
    for (int j = 0; j < 4; j++)
#pragma unroll
        for (int r = 0; r < 4; r++) {
            const int row = i * 16 + quad * 4 + r, col = j * 16 + l15;
            Pb[row * 64 + col]        = aKV[j][r];
            Pb[4096 + row * 64 + col] = aQV[j][r];
            Pb[8192 + row * 64 + col] = aQQ[j][r];
        }
}

// Sum the 16 slabs per head: M[head][3*4096]
__global__ __launch_bounds__(256) void gram_reduce(const float* __restrict__ P,
                                                   float* __restrict__ M) {
    const int o = blockIdx.x * 256 + threadIdx.x;   // 0..294911
    const int head = o / 12288, e = o % 12288;
    const float* Pb = P + (size_t)head * 16 * 12288 + e;
    float s = 0.f;
#pragma unroll
    for (int k = 0; k < 16; k++) s += Pb[(size_t)k * 12288];
    M[o] = s;
}

// ---------------------------------------------------------------------------
// W = 0.1*s*Mqv - 0.1*s^2 * (Mqq @ Mkv); emit TRANSPOSED bf16 Wt[d][k].
// ---------------------------------------------------------------------------
__global__ __launch_bounds__(256) void combine_w(const float* __restrict__ M,
                                                 HBF* __restrict__ Wt) {
    const int bh = blockIdx.x;
    const int by = blockIdx.y;
    const int t = threadIdx.x;
    __shared__ float Kv[4096];
    __shared__ float Qq8[512];
    const float* Mb = M + (size_t)bh * 12288;
#pragma unroll
    for (int r = 0; r < 16; r++) Kv[t + 256 * r] = Mb[t + 256 * r];
#pragma unroll
    for (int r = 0; r < 2; r++)  Qq8[t + 256 * r] = Mb[8192 + by * 512 + t + 256 * r];
    __syncthreads();

    const int il = t >> 5;
    const int j0 = (t & 31) * 2;
    float s0 = 0.f, s1 = 0.f;
#pragma unroll
    for (int k = 0; k < 64; k++) {
        const float q = Qq8[il * 64 + k];
        const float2 kv = *(const float2*)&Kv[k * 64 + j0];
        s0 += q * kv.x;
        s1 += q * kv.y;
    }
    const int i = by * 8 + il;
    const float w0 = STEP_C * (SCALE_C * Mb[4096 + i * 64 + j0]     - SCALE_C * SCALE_C * s0);
    const float w1 = STEP_C * (SCALE_C * Mb[4096 + i * 64 + j0 + 1] - SCALE_C * SCALE_C * s1);
    Wt[(size_t)bh * 4096 + j0 * 64 + i]       = __float2bfloat16(w0);
    Wt[(size_t)bh * 4096 + (j0 + 1) * 64 + i] = __float2bfloat16(w1);
}

// ---------------------------------------------------------------------------
// MFMA epilogue: AO[b,n,h*64+d] = relu(V + (Kn @ W)[n][d] - 0.05), bf16.
// Kn is pre-normalized. global_load_lds staging for Kn + Wt.
// ---------------------------------------------------------------------------
__global__ __launch_bounds__(256) void epilogue_attn(const HBF* __restrict__ Kn,
                                                     const HBF* __restrict__ Vb,
                                                     const HBF* __restrict__ Wt,
                                                     HBF* __restrict__ AO) {
    __shared__ char smem[34816];
    HBF* Ks  = (HBF*)smem;            // [128][64] swizzled (16 KB)
    HBF* Wts = Ks + 128 * 64;         // [64][64]  swizzled (8 KB)
    float* Ps = (float*)smem;         // phase 2: 4 waves x [32][68] fp32

    const int bh = blockIdx.x, cn = blockIdx.y;
    const int b = bh / 12, h = bh % 12;
    const int t = threadIdx.x, wv = t >> 6, lane = t & 63;
    const int l15 = lane & 15, quad = lane >> 4;
    const size_t kbase = ((size_t)bh * 2048 + cn * 128) * 64;
    const int srow = lane >> 3;
    const int schunk = (lane & 7) ^ srow;
    const int sub = t & 7;

#pragma unroll
    for (int rg = 0; rg < 4; rg++) {
        const int region = rg * 4 + wv;            // 0..15
        const int row = region * 8 + srow;
        __builtin_amdgcn_global_load_lds((const void*)(Kn + kbase + (size_t)row * 64 + schunk * 8),
                                         (void*)(Ks + region * 512), 16, 0, 0);
    }
#pragma unroll
    for (int rg = 0; rg < 2; rg++) {
        const int region = rg * 4 + wv;            // 0..7
        const int row = region * 8 + srow;
        __builtin_amdgcn_global_load_lds((const void*)(Wt + (size_t)bh * 4096 + (size_t)row * 64 + schunk * 8),
                                         (void*)(Wts + region * 512), 16, 0, 0);
    }
    __syncthreads();

    f32x4 acc[2][4] = {};
#pragma unroll
    for (int s = 0; s < 2; s++) {
        const int ch = (s * 4 + quad) ^ (l15 & 7);
        bf16x8 af[2], bfr[4];
#pragma unroll
        for (int i = 0; i < 2; i++) {
            const int row = wv * 32 + i * 16 + l15;
            af[i] = *reinterpret_cast<const bf16x8*>(&Ks[row * 64 + ch * 8]);
        }
#pragma unroll
        for (int j = 0; j < 4; j++) {
            const int d = j * 16 + l15;
            bfr[j] = *reinterpret_cast<const bf16x8*>(&Wts[d * 64 + ch * 8]);
        }
#pragma unroll
        for (int i = 0; i < 2; i++)
#pragma unroll
            for (int j = 0; j < 4; j++)
                acc[i][j] = __builtin_amdgcn_mfma_f32_16x16x32_bf16(af[i], bfr[j], acc[i][j], 0, 0, 0);
    }
    __syncthreads();   // Ks/Wts dead; reuse LDS for P

    float* Pw = Ps + wv * (32 * 68);
#pragma unroll
    for (int i = 0; i < 2; i++)
#pragma unroll
        for (int j = 0; j < 4; j++)
#pragma unroll
            for (int r = 0; r < 4; r++)
                Pw[(i * 16 + quad * 4 + r) * 68 + j * 16 + l15] = acc[i][j][r];
    __syncthreads();

#pragma unroll
    for (int rr = 0; rr < 4; rr++) {
        const int row = rr * 32 + (t >> 3);       // 0..127
        const float* prow = Ps + (row >> 5) * (32 * 68) + (row & 31) * 68 + sub * 8;
        const float4 p0 = *(const float4*)prow;
        const float4 p1 = *(const float4*)(prow + 4);
        uint4 rv = *(const uint4*)(Vb + kbase + (size_t)row * 64 + sub * 8);
        const HBF* hv = (const HBF*)&rv;
        const float pv[8] = {p0.x, p0.y, p0.z, p0.w, p1.x, p1.y, p1.z, p1.w};
        HBF o[8];
#pragma unroll
        for (int i = 0; i < 8; i++)
            o[i] = __float2bfloat16(fmaxf(__bfloat162float(hv[i]) + pv[i] - (STEP_C * LAMBD_C), 0.f));
        const int n = cn * 128 + row;
        *(uint4*)(AO + ((size_t)b * 2048 + n) * 768 + h * 64 + sub * 8) = *(const uint4*)o;
    }
}

// ---------------------------------------------------------------------------
extern "C" void kernel_launch(void* const* d_in, const int* in_sizes, int n_in,
                              void* d_out, int out_size, void* d_ws, size_t ws_size,
                              hipStream_t stream) {
    char* ws = (char*)d_ws;
    size_t off = 0;
    int*   flag   = (int*)(ws + off);   off += 16;
    HBF*   xb     = (HBF*)(ws + off);   off += (size_t)4096 * 768 * 2;
    HBF*   Wqkvb  = (HBF*)(ws + off);   off += (size_t)2304 * 768 * 2;
    HBF*   Wprojb = (HBF*)(ws + off);   off += (size_t)768 * 768 * 2;
    HBF*   bprojb = (HBF*)(ws + off);   off += 2048;
    HBF*   Kn     = (HBF*)(ws + off);   off += (size_t)24 * 2048 * 64 * 2;
    HBF*   Vb     = (HBF*)(ws + off);   off += (size_t)24 * 2048 * 64 * 2;
    HBF*   QKVt   = (HBF*)(ws + off);   off += (size_t)3 * 24 * 64 * 2048 * 2;
    float* P      = (float*)(ws + off); off += (size_t)24 * 16 * 12288 * 4;
    float* M      = (float*)(ws + off); off += (size_t)24 * 12288 * 4;
    HBF*   Wt     = (HBF*)(ws + off);   off += (size_t)24 * 4096 * 2;
    HBF*   AO     = (HBF*)(ws + off);   off += (size_t)4096 * 768 * 2;
    // total ~69 MB

    // 0) one fused dtype-detect + convert pass
    convert_all<<<2048, 256, 0, stream>>>(d_in[0], d_in[1], d_in[2], d_in[3],
                                          xb, Wqkvb, Wprojb, bprojb, flag);

    // 1) qkv GEMM: fused L2-norm + head-split natural (Kn, V) + transposed (QKVt)
    gemm128<4, false, false, true><<<dim3(32, 18), 256, 0, stream>>>(
        xb, Wqkvb, nullptr, nullptr, Kn, Vb, QKVt, 4096, 2304, 768, nullptr);

    // 2) MFMA Gram partials + tree reduce
    gram_mfma<<<dim3(24, 16), 256, 0, stream>>>(QKVt, P);
    gram_reduce<<<1152, 256, 0, stream>>>(P, M);

    // 3) W combine -> transposed bf16 Wt
    combine_w<<<dim3(24, 8), 256, 0, stream>>>(M, Wt);

    // 4) MFMA epilogue: relu(V + Kn@W - 0.05) -> [B,N,C] bf16
    epilogue_attn<<<dim3(24, 16), 256, 0, stream>>>(Kn, Vb, Wt, AO);

    // 5) out = AO @ Wproj^T + bproj
    gemm128<2, true, true, false><<<dim3(32, 12), 256, 0, stream>>>(
        AO, Wprojb, bprojb, d_out, nullptr, nullptr, nullptr, 4096, 768, 768, flag);
}

// Round 8
// 142.797 us; speedup vs baseline: 2.1654x; 1.0747x over previous
//
#include <hip/hip_runtime.h>
#include <hip/hip_bf16.h>

typedef __attribute__((ext_vector_type(8))) __bf16 bf16x8;
typedef __attribute__((ext_vector_type(4))) float f32x4;

#define HBF __hip_bfloat16

// B=2, N=2048, C=768, H=12, D=64
static constexpr float SCALE_C = 0.125f;   // D^-0.5
static constexpr float STEP_C  = 0.1f;
static constexpr float LAMBD_C = 0.5f;

__device__ __forceinline__ int sane_f(float v) {
    float a = fabsf(v);
    return (a <= 1.0e4f && (a >= 1.0e-6f || v == 0.0f)) ? 1 : 0;   // NaN -> 0
}

// ---------------------------------------------------------------------------
// Fused dtype-detect + canonicalize ALL inputs to bf16 in ONE launch.
// ---------------------------------------------------------------------------
__global__ __launch_bounds__(256) void convert_all(const void* __restrict__ x,
                                                   const void* __restrict__ wqkv,
                                                   const void* __restrict__ wproj,
                                                   const void* __restrict__ bproj,
                                                   HBF* __restrict__ xb,
                                                   HBF* __restrict__ wqkvb,
                                                   HBF* __restrict__ wprojb,
                                                   HBF* __restrict__ bprojb,
                                                   int* __restrict__ flag) {
    const int t = threadIdx.x, lane = t & 63;
    const unsigned int w = ((const unsigned int*)x)[lane];
    const float f  = __uint_as_float(w);
    const float h0 = __uint_as_float((w & 0xFFFFu) << 16);
    const float h1 = __uint_as_float(w & 0xFFFF0000u);
    int s32 = sane_f(f);
    int s16 = sane_f(h0) + sane_f(h1);
#pragma unroll
    for (int off = 32; off >= 1; off >>= 1) {
        s32 += __shfl_xor(s32, off, 64);
        s16 += __shfl_xor(s16, off, 64);
    }
    const int isf32 = (2 * s32 >= s16) ? 1 : 0;
    if (blockIdx.x == 0 && t == 0) flag[0] = isf32;

    constexpr int C0 = (4096 * 768) / 8;
    constexpr int C1 = C0 + (2304 * 768) / 8;
    constexpr int C2 = C1 + (768 * 768) / 8;
    constexpr int C3 = C2 + 768 / 8;

    int i = blockIdx.x * 256 + t;
    const int stride = gridDim.x * 256;
    for (; i < C3; i += stride) {
        const void* src; HBF* dst; int e;
        if (i < C0)      { src = x;     dst = xb;     e = i; }
        else if (i < C1) { src = wqkv;  dst = wqkvb;  e = i - C0; }
        else if (i < C2) { src = wproj; dst = wprojb; e = i - C1; }
        else             { src = bproj; dst = bprojb; e = i - C2; }
        if (isf32) {
            const float4* s = (const float4*)src;
            float4 a = s[2 * e], b = s[2 * e + 1];
            HBF o[8] = {__float2bfloat16(a.x), __float2bfloat16(a.y),
                        __float2bfloat16(a.z), __float2bfloat16(a.w),
                        __float2bfloat16(b.x), __float2bfloat16(b.y),
                        __float2bfloat16(b.z), __float2bfloat16(b.w)};
            ((uint4*)dst)[e] = *(const uint4*)o;
        } else {
            ((uint4*)dst)[e] = ((const uint4*)src)[e];
        }
    }
}

// ---------------------------------------------------------------------------
// Double-buffered bf16 GEMM, B^T layout: C[m,n]=sum_k A[m,k]B[n,k] (+bias)
// Tile TM x TN, 256 thr = 4 waves (2x2); wave tile (TM/2)x(TN/2).
// K-loop: barrier -> issue(k+1 into other buf) -> compute(cur buf): the next
// barrier's vmcnt(0) drain overlaps with this iteration's MFMA+ds_reads.
// SPLITQKV (TM=64,TN=128): fused fp32 L2-norm of Q/K rows; writes Kn/V
// natural [bh][n][64] and QKVt transposed [3][bh][64][2048].
// FINAL: out dtype per runtime flag (1->fp32 scalar, 0->bf16 vector).
// ---------------------------------------------------------------------------
template <int TM, int TN, bool BIAS, bool FINAL, bool SPLITQKV>
__global__ __launch_bounds__(256) void gemm_db(const HBF* __restrict__ A,
                                               const HBF* __restrict__ B,
                                               const HBF* __restrict__ bias,
                                               void* __restrict__ Cout,
                                               HBF* __restrict__ knat,
                                               HBF* __restrict__ vnat,
                                               HBF* __restrict__ tbuf,
                                               int M, int N, int K,
                                               const int* __restrict__ flagp) {
    constexpr int NI = TM / 32;            // 16-row strips per wave
    constexpr int NJ = TN / 32;            // 16-col strips per wave
    constexpr int BUF = (TM + TN) * 64;    // HBF elems per LDS buffer
    __shared__ HBF smem[2 * BUF];

    int outf32 = 0;
    if (FINAL) outf32 = *flagp;

    const int tid  = threadIdx.x;
    const int wv   = tid >> 6, lane = tid & 63;
    const int m0   = blockIdx.x * TM, n0 = blockIdx.y * TN;
    const int wr = wv >> 1, wc = wv & 1;
    const int l15 = lane & 15, quad = lane >> 4;
    const int srow   = lane >> 3;
    const int schunk = (lane & 7) ^ srow;

    const int NITER = K / 64;

    auto issue = [&](int it) {
        HBF* abase = smem + (it & 1) * BUF;
        HBF* bbase = abase + TM * 64;
        const int k0 = it * 64;
#pragma unroll
        for (int d = 0; d < NI; d++) {
            const int region = d * 4 + wv;
            const int row = region * 8 + srow;
            __builtin_amdgcn_global_load_lds((const void*)(A + (size_t)(m0 + row) * K + k0 + schunk * 8),
                                             (void*)(abase + region * 512), 16, 0, 0);
        }
#pragma unroll
        for (int d = 0; d < NJ; d++) {
            const int region = d * 4 + wv;
            const int row = region * 8 + srow;
            __builtin_amdgcn_global_load_lds((const void*)(B + (size_t)(n0 + row) * K + k0 + schunk * 8),
                                             (void*)(bbase + region * 512), 16, 0, 0);
        }
    };

    f32x4 acc[NI][NJ] = {};

    issue(0);
    for (int it = 0; it < NITER; it++) {
        __syncthreads();               // drains my buf[it&1] loads; syncs readers
        if (it + 1 < NITER) issue(it + 1);   // in flight during compute below
        const HBF* As = smem + (it & 1) * BUF;
        const HBF* Bs = As + TM * 64;
#pragma unroll
        for (int s = 0; s < 2; s++) {
            bf16x8 af[NI], bfr[NJ];
#pragma unroll
            for (int i = 0; i < NI; i++) {
                const int row = wr * (TM / 2) + i * 16 + l15;
                const int ch = (s * 4 + quad) ^ (row & 7);
                af[i] = *reinterpret_cast<const bf16x8*>(&As[row * 64 + ch * 8]);
            }
#pragma unroll
            for (int j = 0; j < NJ; j++) {
                const int col = wc * (TN / 2) + j * 16 + l15;
                const int ch = (s * 4 + quad) ^ (col & 7);
                bfr[j] = *reinterpret_cast<const bf16x8*>(&Bs[col * 64 + ch * 8]);
            }
#pragma unroll
            for (int i = 0; i < NI; i++)
#pragma unroll
                for (int j = 0; j < NJ; j++)
                    acc[i][j] = __builtin_amdgcn_mfma_f32_16x16x32_bf16(af[i], bfr[j], acc[i][j], 0, 0, 0);
        }
    }
    __syncthreads();   // all frag reads done; smem reusable for epilogues

    if (SPLITQKV) {
        // ---- fused split epilogue (TM=64, TN=128; wave = 32 rows x 64 cols) ----
        HBF* wpriv = smem + wv * 4096;   // 8 KB wave-private scratch
        const int colbase = n0 + wc * 64;
        const int tsel = (colbase >= 1536) ? 2 : (colbase >= 768 ? 1 : 0);
        const int h = (colbase - tsel * 768) >> 6;

        if (tsel < 2) {   // L2-normalize rows (fp32, in-register)
#pragma unroll
            for (int i = 0; i < NI; i++)
#pragma unroll
                for (int r = 0; r < 4; r++) {
                    float ss = acc[i][0][r] * acc[i][0][r] + acc[i][1][r] * acc[i][1][r]
                             + acc[i][2][r] * acc[i][2][r] + acc[i][3][r] * acc[i][3][r];
#pragma unroll
                    for (int off = 1; off <= 8; off <<= 1) ss += __shfl_xor(ss, off, 64);
                    const float inv = 1.0f / fmaxf(sqrtf(ss), 1e-12f);
#pragma unroll
                    for (int j = 0; j < 4; j++) acc[i][j][r] *= inv;
                }
        }

        const int rowstart = m0 + wr * 32;
        const int b = rowstart >> 11, nloc = rowstart & 2047;
        const size_t bh = (size_t)(b * 12 + h);

        if (tsel != 0) {   // natural store (K normalized, V plain)
            HBF* ep = wpriv;   // [32][72]
#pragma unroll
            for (int i = 0; i < NI; i++)
#pragma unroll
                for (int j = 0; j < 4; j++)
#pragma unroll
                    for (int r = 0; r < 4; r++)
                        ep[(i * 16 + quad * 4 + r) * 72 + j * 16 + l15] =
                            __float2bfloat16(acc[i][j][r]);
            HBF* dst0 = ((tsel == 2) ? vnat : knat) + (bh * 2048 + nloc) * 64;
#pragma unroll
            for (int itr = 0; itr < 4; itr++) {
                const int idx = itr * 64 + lane;
                const int rl = idx >> 3, ch = idx & 7;
                const uint4 val = *(const uint4*)((const char*)ep + rl * 144 + ch * 16);
                *(uint4*)((char*)dst0 + rl * 128 + ch * 16) = val;
            }
        }
        {   // transposed store -> QKVt[tsel][bh][d][n]
            HBF* epT = wpriv;  // [64][34]
#pragma unroll
            for (int i = 0; i < NI; i++)
#pragma unroll
                for (int j = 0; j < 4; j++)
#pragma unroll
                    for (int r = 0; r < 4; r++)
                        epT[(j * 16 + l15) * 34 + i * 16 + quad * 4 + r] =
                            __float2bfloat16(acc[i][j][r]);
            HBF* tdst = tbuf + (size_t)tsel * (24 * 64 * 2048) + (bh * 64) * 2048 + nloc;
#pragma unroll
            for (int itr = 0; itr < 4; itr++) {
                const int idx = itr * 64 + lane;
                const int d = idx >> 2, c = idx & 3;
                const uint4 val = *(const uint4*)(epT + d * 34 + c * 8);
                *(uint4*)(tdst + (size_t)d * 2048 + c * 8) = val;
            }
        }
        return;
    }

    // ---- plain epilogue ----
    float bvals[NJ];
#pragma unroll
    for (int j = 0; j < NJ; j++) {
        bvals[j] = 0.f;
        if (BIAS) bvals[j] = __bfloat162float(bias[n0 + wc * (TN / 2) + j * 16 + l15]);
    }

    if (FINAL && outf32) {
#pragma unroll
        for (int i = 0; i < NI; i++)
#pragma unroll
            for (int j = 0; j < NJ; j++) {
                const int col = n0 + wc * (TN / 2) + j * 16 + l15;
#pragma unroll
                for (int r = 0; r < 4; r++) {
                    const int row = m0 + wr * (TM / 2) + i * 16 + quad * 4 + r;
                    ((float*)Cout)[(size_t)row * N + col] = acc[i][j][r] + bvals[j];
                }
            }
        return;
    }

    constexpr int RS = (TN / 2) + 8;        // staged row stride (elems)
    constexpr int CHR = TN / 16;            // 16B chunks per staged row
    constexpr int ITERS = 32 * CHR / 64;
    HBF* ep = smem + wv * (32 * RS);

#pragma unroll
    for (int i = 0; i < NI; i++)
#pragma unroll
        for (int j = 0; j < NJ; j++)
#pragma unroll
            for (int r = 0; r < 4; r++)
                ep[(i * 16 + quad * 4 + r) * RS + j * 16 + l15] =
                    __float2bfloat16(acc[i][j][r] + bvals[j]);
    const int rowstart = m0 + wr * 32;
#pragma unroll
    for (int itr = 0; itr < ITERS; itr++) {
        const int idx = itr * 64 + lane;
        const int rl = idx / CHR, ch = idx % CHR;
        const uint4 val = *(const uint4*)((const char*)ep + rl * (RS * 2) + ch * 16);
        *(uint4*)((HBF*)Cout + (size_t)(rowstart + rl) * N + n0 + wc * (TN / 2) + ch * 8) = val;
    }
}

// ---------------------------------------------------------------------------
// MFMA Gram partials from transposed tensors. Block = (head, 128-n chunk).
// ---------------------------------------------------------------------------
__global__ __launch_bounds__(256) void gram_mfma(const HBF* __restrict__ QKVt,
                                                 float* __restrict__ P) {
    __shared__ HBF lds[3 * 8192];   // 48 KB
    const int bh = blockIdx.x, cn = blockIdx.y;
    const int t = threadIdx.x, wv = t >> 6, lane = t & 63;
    const int l15 = lane & 15, quad = lane >> 4;
    constexpr size_t S = (size_t)24 * 64 * 2048;
    const HBF* srcs[3] = {QKVt + S, QKVt, QKVt + 2 * S};   // K, Q, V

    const int rowq = lane >> 4;
    const int cgb  = lane & 15;
#pragma unroll
    for (int t3 = 0; t3 < 3; t3++) {
        const HBF* base = srcs[t3] + (size_t)bh * 64 * 2048 + cn * 128;
#pragma unroll
        for (int rg = 0; rg < 4; rg++) {
            const int region = rg * 4 + wv;
            const int row = region * 4 + rowq;
            const int cg = cgb ^ (row & 15);
            __builtin_amdgcn_global_load_lds((const void*)(base + (size_t)row * 2048 + cg * 8),
                                             (void*)(lds + t3 * 8192 + region * 512), 16, 0, 0);
        }
    }
    __syncthreads();

    const HBF* Kt = lds;
    const HBF* Qt = lds + 8192;
    const HBF* Vt = lds + 16384;
    f32x4 aKV[4] = {}, aQV[4] = {}, aQQ[4] = {};
    const int i = wv;
#pragma unroll
    for (int s = 0; s < 4; s++) {
        const int q = (s * 4 + quad) ^ l15;
        const bf16x8 aK = *(const bf16x8*)(Kt + (i * 16 + l15) * 128 + q * 8);
        const bf16x8 aQ = *(const bf16x8*)(Qt + (i * 16 + l15) * 128 + q * 8);
#pragma unroll
        for (int j = 0; j < 4; j++) {
            const bf16x8 bV = *(const bf16x8*)(Vt + (j * 16 + l15) * 128 + q * 8);
            const bf16x8 bQ = *(const bf16x8*)(Qt + (j * 16 + l15) * 128 + q * 8);
            aKV[j] = __builtin_amdgcn_mfma_f32_16x16x32_bf16(aK, bV, aKV[j], 0, 0, 0);
            aQV[j] = __builtin_amdgcn_mfma_f32_16x16x32_bf16(aQ, bV, aQV[j], 0, 0, 0);
            aQQ[j] = __builtin_amdgcn_mfma_f32_16x16x32_bf16(aQ, bQ, aQQ[j], 0, 0, 0);
        }
    }

    float* Pb = P + ((size_t)bh * 16 + cn) * 12288;
#pragma unroll
    for (int j = 0; j < 4; j++)
#pragma unroll
        for (int r = 0; r < 4; r++) {
            const int row = i * 16 + quad * 4 + r, col = j * 16 + l15;
            Pb[row * 64 + col]        = aKV[j][r];
            Pb[4096 + row * 64 + col] = aQV[j][r];
            Pb[8192 + row * 64 + col] = aQQ[j][r];
        }
}

// Sum the 16 slabs per head
__global__ __launch_bounds__(256) void gram_reduce(const float* __restrict__ P,
                                                   float* __restrict__ M) {
    const int o = blockIdx.x * 256 + threadIdx.x;
    const int head = o / 12288, e = o % 12288;
    const float* Pb = P + (size_t)head * 16 * 12288 + e;
    float s = 0.f;
#pragma unroll
    for (int k = 0; k < 16; k++) s += Pb[(size_t)k * 12288];
    M[o] = s;
}

// ---------------------------------------------------------------------------
// W = 0.1*s*Mqv - 0.1*s^2 * (Mqq @ Mkv); emit TRANSPOSED bf16 Wt[d][k].
// ---------------------------------------------------------------------------
__global__ __launch_bounds__(256) void combine_w(const float* __restrict__ M,
                                                 HBF* __restrict__ Wt) {
    const int bh = blockIdx.x;
    const int by = blockIdx.y;
    const int t = threadIdx.x;
    __shared__ float Kv[4096];
    __shared__ float Qq8[512];
    const float* Mb = M + (size_t)bh * 12288;
#pragma unroll
    for (int r = 0; r < 16; r++) Kv[t + 256 * r] = Mb[t + 256 * r];
#pragma unroll
    for (int r = 0; r < 2; r++)  Qq8[t + 256 * r] = Mb[8192 + by * 512 + t + 256 * r];
    __syncthreads();

    const int il = t >> 5;
    const int j0 = (t & 31) * 2;
    float s0 = 0.f, s1 = 0.f;
#pragma unroll
    for (int k = 0; k < 64; k++) {
        const float q = Qq8[il * 64 + k];
        const float2 kv = *(const float2*)&Kv[k * 64 + j0];
        s0 += q * kv.x;
        s1 += q * kv.y;
    }
    const int i = by * 8 + il;
    const float w0 = STEP_C * (SCALE_C * Mb[4096 + i * 64 + j0]     - SCALE_C * SCALE_C * s0);
    const float w1 = STEP_C * (SCALE_C * Mb[4096 + i * 64 + j0 + 1] - SCALE_C * SCALE_C * s1);
    Wt[(size_t)bh * 4096 + j0 * 64 + i]       = __float2bfloat16(w0);
    Wt[(size_t)bh * 4096 + (j0 + 1) * 64 + i] = __float2bfloat16(w1);
}

// ---------------------------------------------------------------------------
// MFMA epilogue: AO[b,n,h*64+d] = relu(V + (Kn @ W)[n][d] - 0.05), bf16.
// ---------------------------------------------------------------------------
__global__ __launch_bounds__(256) void epilogue_attn(const HBF* __restrict__ Kn,
                                                     const HBF* __restrict__ Vb,
                                                     const HBF* __restrict__ Wt,
                                                     HBF* __restrict__ AO) {
    __shared__ char smem[34816];
    HBF* Ks  = (HBF*)smem;
    HBF* Wts = Ks + 128 * 64;
    float* Ps = (float*)smem;

    const int bh = blockIdx.x, cn = blockIdx.y;
    const int b = bh / 12, h = bh % 12;
    const int t = threadIdx.x, wv = t >> 6, lane = t & 63;
    const int l15 = lane & 15, quad = lane >> 4;
    const size_t kbase = ((size_t)bh * 2048 + cn * 128) * 64;
    const int srow = lane >> 3;
    const int schunk = (lane & 7) ^ srow;
    const int sub = t & 7;

#pragma unroll
    for (int rg = 0; rg < 4; rg++) {
        const int region = rg * 4 + wv;
        const int row = region * 8 + srow;
        __builtin_amdgcn_global_load_lds((const void*)(Kn + kbase + (size_t)row * 64 + schunk * 8),
                                         (void*)(Ks + region * 512), 16, 0, 0);
    }
#pragma unroll
    for (int rg = 0; rg < 2; rg++) {
        const int region = rg * 4 + wv;
        const int row = region * 8 + srow;
        __builtin_amdgcn_global_load_lds((const void*)(Wt + (size_t)bh * 4096 + (size_t)row * 64 + schunk * 8),
                                         (void*)(Wts + region * 512), 16, 0, 0);
    }
    __syncthreads();

    f32x4 acc[2][4] = {};
#pragma unroll
    for (int s = 0; s < 2; s++) {
        const int ch = (s * 4 + quad) ^ (l15 & 7);
        bf16x8 af[2], bfr[4];
#pragma unroll
        for (int i = 0; i < 2; i++) {
            const int row = wv * 32 + i * 16 + l15;
            af[i] = *reinterpret_cast<const bf16x8*>(&Ks[row * 64 + ch * 8]);
        }
#pragma unroll
        for (int j = 0; j < 4; j++) {
            const int d = j * 16 + l15;
            bfr[j] = *reinterpret_cast<const bf16x8*>(&Wts[d * 64 + ch * 8]);
        }
#pragma unroll
        for (int i = 0; i < 2; i++)
#pragma unroll
            for (int j = 0; j < 4; j++)
                acc[i][j] = __builtin_amdgcn_mfma_f32_16x16x32_bf16(af[i], bfr[j], acc[i][j], 0, 0, 0);
    }
    __syncthreads();

    float* Pw = Ps + wv * (32 * 68);
#pragma unroll
    for (int i = 0; i < 2; i++)
#pragma unroll
        for (int j = 0; j < 4; j++)
#pragma unroll
            for (int r = 0; r < 4; r++)
                Pw[(i * 16 + quad * 4 + r) * 68 + j * 16 + l15] = acc[i][j][r];
    __syncthreads();

#pragma unroll
    for (int rr = 0; rr < 4; rr++) {
        const int row = rr * 32 + (t >> 3);
        const float* prow = Ps + (row >> 5) * (32 * 68) + (row & 31) * 68 + sub * 8;
        const float4 p0 = *(const float4*)prow;
        const float4 p1 = *(const float4*)(prow + 4);
        uint4 rv = *(const uint4*)(Vb + kbase + (size_t)row * 64 + sub * 8);
        const HBF* hv = (const HBF*)&rv;
        const float pv[8] = {p0.x, p0.y, p0.z, p0.w, p1.x, p1.y, p1.z, p1.w};
        HBF o[8];
#pragma unroll
        for (int i = 0; i < 8; i++)
            o[i] = __float2bfloat16(fmaxf(__bfloat162float(hv[i]) + pv[i] - (STEP_C * LAMBD_C), 0.f));
        const int n = cn * 128 + row;
        *(uint4*)(AO + ((size_t)b * 2048 + n) * 768 + h * 64 + sub * 8) = *(const uint4*)o;
    }
}

// ---------------------------------------------------------------------------
extern "C" void kernel_launch(void* const* d_in, const int* in_sizes, int n_in,
                              void* d_out, int out_size, void* d_ws, size_t ws_size,
                              hipStream_t stream) {
    char* ws = (char*)d_ws;
    size_t off = 0;
    int*   flag   = (int*)(ws + off);   off += 16;
    HBF*   xb     = (HBF*)(ws + off);   off += (size_t)4096 * 768 * 2;
    HBF*   Wqkvb  = (HBF*)(ws + off);   off += (size_t)2304 * 768 * 2;
    HBF*   Wprojb = (HBF*)(ws + off);   off += (size_t)768 * 768 * 2;
    HBF*   bprojb = (HBF*)(ws + off);   off += 2048;
    HBF*   Kn     = (HBF*)(ws + off);   off += (size_t)24 * 2048 * 64 * 2;
    HBF*   Vb     = (HBF*)(ws + off);   off += (size_t)24 * 2048 * 64 * 2;
    HBF*   QKVt   = (HBF*)(ws + off);   off += (size_t)3 * 24 * 64 * 2048 * 2;
    float* P      = (float*)(ws + off); off += (size_t)24 * 16 * 12288 * 4;
    float* M      = (float*)(ws + off); off += (size_t)24 * 12288 * 4;
    HBF*   Wt     = (HBF*)(ws + off);   off += (size_t)24 * 4096 * 2;
    HBF*   AO     = (HBF*)(ws + off);   off += (size_t)4096 * 768 * 2;
    // total ~69 MB

    // 0) one fused dtype-detect + convert pass
    convert_all<<<2048, 256, 0, stream>>>(d_in[0], d_in[1], d_in[2], d_in[3],
                                          xb, Wqkvb, Wprojb, bprojb, flag);

    // 1) qkv GEMM (double-buffered, 64x128 tiles, 1152 blocks):
    //    fused L2-norm + head-split natural (Kn, V) + transposed (QKVt)
    gemm_db<64, 128, false, false, true><<<dim3(64, 18), 256, 0, stream>>>(
        xb, Wqkvb, nullptr, nullptr, Kn, Vb, QKVt, 4096, 2304, 768, nullptr);

    // 2) MFMA Gram partials + tree reduce
    gram_mfma<<<dim3(24, 16), 256, 0, stream>>>(QKVt, P);
    gram_reduce<<<1152, 256, 0, stream>>>(P, M);

    // 3) W combine -> transposed bf16 Wt
    combine_w<<<dim3(24, 8), 256, 0, stream>>>(M, Wt);

    // 4) MFMA epilogue: relu(V + Kn@W - 0.05) -> [B,N,C] bf16
    epilogue_attn<<<dim3(24, 16), 256, 0, stream>>>(Kn, Vb, Wt, AO);

    // 5) out = AO @ Wproj^T + bproj (double-buffered, 64x64 tiles, 768 blocks)
    gemm_db<64, 64, true, true, false><<<dim3(64, 12), 256, 0, stream>>>(
        AO, Wprojb, bprojb, d_out, nullptr, nullptr, nullptr, 4096, 768, 768, flag);
}

// Round 9
// 140.090 us; speedup vs baseline: 2.2072x; 1.0193x over previous
//
#include <hip/hip_runtime.h>
#include <hip/hip_bf16.h>

typedef __attribute__((ext_vector_type(8))) __bf16 bf16x8;
typedef __attribute__((ext_vector_type(4))) float f32x4;

#define HBF __hip_bfloat16

// B=2, N=2048, C=768, H=12, D=64
static constexpr float SCALE_C = 0.125f;   // D^-0.5
static constexpr float STEP_C  = 0.1f;
static constexpr float LAMBD_C = 0.5f;

__device__ __forceinline__ int sane_f(float v) {
    float a = fabsf(v);
    return (a <= 1.0e4f && (a >= 1.0e-6f || v == 0.0f)) ? 1 : 0;   // NaN -> 0
}

// ---------------------------------------------------------------------------
// Dtype-detect; canonicalize to bf16 ONLY if inputs are fp32 (else early-exit:
// GEMMs read the raw bf16 inputs directly).
// ---------------------------------------------------------------------------
__global__ __launch_bounds__(256) void convert_all(const void* __restrict__ x,
                                                   const void* __restrict__ wqkv,
                                                   const void* __restrict__ wproj,
                                                   const void* __restrict__ bproj,
                                                   HBF* __restrict__ xb,
                                                   HBF* __restrict__ wqkvb,
                                                   HBF* __restrict__ wprojb,
                                                   HBF* __restrict__ bprojb,
                                                   int* __restrict__ flag) {
    const int t = threadIdx.x, lane = t & 63;
    const unsigned int w = ((const unsigned int*)x)[lane];
    const float f  = __uint_as_float(w);
    const float h0 = __uint_as_float((w & 0xFFFFu) << 16);
    const float h1 = __uint_as_float(w & 0xFFFF0000u);
    int s32 = sane_f(f);
    int s16 = sane_f(h0) + sane_f(h1);
#pragma unroll
    for (int off = 32; off >= 1; off >>= 1) {
        s32 += __shfl_xor(s32, off, 64);
        s16 += __shfl_xor(s16, off, 64);
    }
    const int isf32 = (2 * s32 >= s16) ? 1 : 0;
    if (blockIdx.x == 0 && t == 0) flag[0] = isf32;
    if (!isf32) return;   // bf16 inputs: GEMMs read d_in directly

    constexpr int C0 = (4096 * 768) / 8;
    constexpr int C1 = C0 + (2304 * 768) / 8;
    constexpr int C2 = C1 + (768 * 768) / 8;
    constexpr int C3 = C2 + 768 / 8;

    int i = blockIdx.x * 256 + t;
    const int stride = gridDim.x * 256;
    for (; i < C3; i += stride) {
        const void* src; HBF* dst; int e;
        if (i < C0)      { src = x;     dst = xb;     e = i; }
        else if (i < C1) { src = wqkv;  dst = wqkvb;  e = i - C0; }
        else if (i < C2) { src = wproj; dst = wprojb; e = i - C1; }
        else             { src = bproj; dst = bprojb; e = i - C2; }
        const float4* s = (const float4*)src;
        float4 a = s[2 * e], b = s[2 * e + 1];
        HBF o[8] = {__float2bfloat16(a.x), __float2bfloat16(a.y),
                    __float2bfloat16(a.z), __float2bfloat16(a.w),
                    __float2bfloat16(b.x), __float2bfloat16(b.y),
                    __float2bfloat16(b.z), __float2bfloat16(b.w)};
        ((uint4*)dst)[e] = *(const uint4*)o;
    }
}

// ---------------------------------------------------------------------------
// Double-buffered bf16 GEMM, B^T layout: C[m,n]=sum_k A[m,k]B[n,k] (+bias)
// A/B/bias given as (converted, raw) pairs; selected by runtime flag.
// Tile TM x TN, 256 thr = 4 waves (2x2); wave tile (TM/2)x(TN/2).
// K-loop: barrier -> issue(k+1 into other buf) -> compute(cur buf).
// SPLITQKV (TM=64,TN=128): fused fp32 L2-norm of Q/K rows; writes Kn/V
// natural [bh][n][64] and QKVt transposed [3][bh][64][2048].
// FINAL: out dtype per runtime flag (1->fp32 scalar, 0->bf16 vector).
// ---------------------------------------------------------------------------
template <int TM, int TN, bool BIAS, bool FINAL, bool SPLITQKV>
__global__ __launch_bounds__(256) void gemm_db(const HBF* __restrict__ Ac,
                                               const void* __restrict__ Ar,
                                               const HBF* __restrict__ Bc,
                                               const void* __restrict__ Br,
                                               const HBF* __restrict__ biasc,
                                               const void* __restrict__ biasr,
                                               void* __restrict__ Cout,
                                               HBF* __restrict__ knat,
                                               HBF* __restrict__ vnat,
                                               HBF* __restrict__ tbuf,
                                               int M, int N, int K,
                                               const int* __restrict__ flagp) {
    constexpr int NI = TM / 32;
    constexpr int NJ = TN / 32;
    constexpr int BUF = (TM + TN) * 64;
    __shared__ HBF smem[2 * BUF];

    const int fl = flagp[0];
    const HBF* A = fl ? Ac : (const HBF*)Ar;
    const HBF* B = fl ? Bc : (const HBF*)Br;
    const HBF* bias = nullptr;
    if (BIAS) bias = fl ? biasc : (const HBF*)biasr;

    const int tid  = threadIdx.x;
    const int wv   = tid >> 6, lane = tid & 63;
    const int m0   = blockIdx.x * TM, n0 = blockIdx.y * TN;
    const int wr = wv >> 1, wc = wv & 1;
    const int l15 = lane & 15, quad = lane >> 4;
    const int srow   = lane >> 3;
    const int schunk = (lane & 7) ^ srow;

    const int NITER = K / 64;

    auto issue = [&](int it) {
        HBF* abase = smem + (it & 1) * BUF;
        HBF* bbase = abase + TM * 64;
        const int k0 = it * 64;
#pragma unroll
        for (int d = 0; d < NI; d++) {
            const int region = d * 4 + wv;
            const int row = region * 8 + srow;
            __builtin_amdgcn_global_load_lds((const void*)(A + (size_t)(m0 + row) * K + k0 + schunk * 8),
                                             (void*)(abase + region * 512), 16, 0, 0);
        }
#pragma unroll
        for (int d = 0; d < NJ; d++) {
            const int region = d * 4 + wv;
            const int row = region * 8 + srow;
            __builtin_amdgcn_global_load_lds((const void*)(B + (size_t)(n0 + row) * K + k0 + schunk * 8),
                                             (void*)(bbase + region * 512), 16, 0, 0);
        }
    };

    f32x4 acc[NI][NJ] = {};

    issue(0);
    for (int it = 0; it < NITER; it++) {
        __syncthreads();
        if (it + 1 < NITER) issue(it + 1);
        const HBF* As = smem + (it & 1) * BUF;
        const HBF* Bs = As + TM * 64;
#pragma unroll
        for (int s = 0; s < 2; s++) {
            bf16x8 af[NI], bfr[NJ];
#pragma unroll
            for (int i = 0; i < NI; i++) {
                const int row = wr * (TM / 2) + i * 16 + l15;
                const int ch = (s * 4 + quad) ^ (row & 7);
                af[i] = *reinterpret_cast<const bf16x8*>(&As[row * 64 + ch * 8]);
            }
#pragma unroll
            for (int j = 0; j < NJ; j++) {
                const int col = wc * (TN / 2) + j * 16 + l15;
                const int ch = (s * 4 + quad) ^ (col & 7);
                bfr[j] = *reinterpret_cast<const bf16x8*>(&Bs[col * 64 + ch * 8]);
            }
#pragma unroll
            for (int i = 0; i < NI; i++)
#pragma unroll
                for (int j = 0; j < NJ; j++)
                    acc[i][j] = __builtin_amdgcn_mfma_f32_16x16x32_bf16(af[i], bfr[j], acc[i][j], 0, 0, 0);
        }
    }
    __syncthreads();

    if (SPLITQKV) {
        HBF* wpriv = smem + wv * 4096;
        const int colbase = n0 + wc * 64;
        const int tsel = (colbase >= 1536) ? 2 : (colbase >= 768 ? 1 : 0);
        const int h = (colbase - tsel * 768) >> 6;

        if (tsel < 2) {
#pragma unroll
            for (int i = 0; i < NI; i++)
#pragma unroll
                for (int r = 0; r < 4; r++) {
                    float ss = acc[i][0][r] * acc[i][0][r] + acc[i][1][r] * acc[i][1][r]
                             + acc[i][2][r] * acc[i][2][r] + acc[i][3][r] * acc[i][3][r];
#pragma unroll
                    for (int off = 1; off <= 8; off <<= 1) ss += __shfl_xor(ss, off, 64);
                    const float inv = 1.0f / fmaxf(sqrtf(ss), 1e-12f);
#pragma unroll
                    for (int j = 0; j < 4; j++) acc[i][j][r] *= inv;
                }
        }

        const int rowstart = m0 + wr * 32;
        const int b = rowstart >> 11, nloc = rowstart & 2047;
        const size_t bh = (size_t)(b * 12 + h);

        if (tsel != 0) {
            HBF* ep = wpriv;   // [32][72]
#pragma unroll
            for (int i = 0; i < NI; i++)
#pragma unroll
                for (int j = 0; j < 4; j++)
#pragma unroll
                    for (int r = 0; r < 4; r++)
                        ep[(i * 16 + quad * 4 + r) * 72 + j * 16 + l15] =
                            __float2bfloat16(acc[i][j][r]);
            HBF* dst0 = ((tsel == 2) ? vnat : knat) + (bh * 2048 + nloc) * 64;
#pragma unroll
            for (int itr = 0; itr < 4; itr++) {
                const int idx = itr * 64 + lane;
                const int rl = idx >> 3, ch = idx & 7;
                const uint4 val = *(const uint4*)((const char*)ep + rl * 144 + ch * 16);
                *(uint4*)((char*)dst0 + rl * 128 + ch * 16) = val;
            }
        }
        {
            HBF* epT = wpriv;  // [64][34]
#pragma unroll
            for (int i = 0; i < NI; i++)
#pragma unroll
                for (int j = 0; j < 4; j++)
#pragma unroll
                    for (int r = 0; r < 4; r++)
                        epT[(j * 16 + l15) * 34 + i * 16 + quad * 4 + r] =
                            __float2bfloat16(acc[i][j][r]);
            HBF* tdst = tbuf + (size_t)tsel * (24 * 64 * 2048) + (bh * 64) * 2048 + nloc;
#pragma unroll
            for (int itr = 0; itr < 4; itr++) {
                const int idx = itr * 64 + lane;
                const int d = idx >> 2, c = idx & 3;
                const uint4 val = *(const uint4*)(epT + d * 34 + c * 8);
                *(uint4*)(tdst + (size_t)d * 2048 + c * 8) = val;
            }
        }
        return;
    }

    float bvals[NJ];
#pragma unroll
    for (int j = 0; j < NJ; j++) {
        bvals[j] = 0.f;
        if (BIAS) bvals[j] = __bfloat162float(bias[n0 + wc * (TN / 2) + j * 16 + l15]);
    }

    if (FINAL && fl) {   // fp32 output path (only when inputs were fp32)
#pragma unroll
        for (int i = 0; i < NI; i++)
#pragma unroll
            for (int j = 0; j < NJ; j++) {
                const int col = n0 + wc * (TN / 2) + j * 16 + l15;
#pragma unroll
                for (int r = 0; r < 4; r++) {
                    const int row = m0 + wr * (TM / 2) + i * 16 + quad * 4 + r;
                    ((float*)Cout)[(size_t)row * N + col] = acc[i][j][r] + bvals[j];
                }
            }
        return;
    }

    constexpr int RS = (TN / 2) + 8;
    constexpr int CHR = TN / 16;
    constexpr int ITERS = 32 * CHR / 64;
    HBF* ep = smem + wv * (32 * RS);

#pragma unroll
    for (int i = 0; i < NI; i++)
#pragma unroll
        for (int j = 0; j < NJ; j++)
#pragma unroll
            for (int r = 0; r < 4; r++)
                ep[(i * 16 + quad * 4 + r) * RS + j * 16 + l15] =
                    __float2bfloat16(acc[i][j][r] + bvals[j]);
    const int rowstart = m0 + wr * 32;
#pragma unroll
    for (int itr = 0; itr < ITERS; itr++) {
        const int idx = itr * 64 + lane;
        const int rl = idx / CHR, ch = idx % CHR;
        const uint4 val = *(const uint4*)((const char*)ep + rl * (RS * 2) + ch * 16);
        *(uint4*)((HBF*)Cout + (size_t)(rowstart + rl) * N + n0 + wc * (TN / 2) + ch * 8) = val;
    }
}

// ---------------------------------------------------------------------------
// MFMA Gram partials. Block = (head, 256-n chunk as two 128 sub-chunks).
// grid (24,8); accumulates across sub-chunks in registers. No atomics.
// ---------------------------------------------------------------------------
__global__ __launch_bounds__(256) void gram_mfma(const HBF* __restrict__ QKVt,
                                                 float* __restrict__ P) {
    __shared__ HBF lds[3 * 8192];   // 48 KB
    const int bh = blockIdx.x, cn = blockIdx.y;
    const int t = threadIdx.x, wv = t >> 6, lane = t & 63;
    const int l15 = lane & 15, quad = lane >> 4;
    constexpr size_t S = (size_t)24 * 64 * 2048;
    const HBF* srcs[3] = {QKVt + S, QKVt, QKVt + 2 * S};   // K, Q, V

    const int rowq = lane >> 4;
    const int cgb  = lane & 15;
    f32x4 aKV[4] = {}, aQV[4] = {}, aQQ[4] = {};
    const int i = wv;

    for (int sub = 0; sub < 2; sub++) {
        if (sub) __syncthreads();   // readers of previous sub done
#pragma unroll
        for (int t3 = 0; t3 < 3; t3++) {
            const HBF* base = srcs[t3] + (size_t)bh * 64 * 2048 + cn * 256 + sub * 128;
#pragma unroll
            for (int rg = 0; rg < 4; rg++) {
                const int region = rg * 4 + wv;
                const int row = region * 4 + rowq;
                const int cg = cgb ^ (row & 15);
                __builtin_amdgcn_global_load_lds((const void*)(base + (size_t)row * 2048 + cg * 8),
                                                 (void*)(lds + t3 * 8192 + region * 512), 16, 0, 0);
            }
        }
        __syncthreads();

        const HBF* Kt = lds;
        const HBF* Qt = lds + 8192;
        const HBF* Vt = lds + 16384;
#pragma unroll
        for (int s = 0; s < 4; s++) {
            const int q = (s * 4 + quad) ^ l15;
            const bf16x8 aK = *(const bf16x8*)(Kt + (i * 16 + l15) * 128 + q * 8);
            const bf16x8 aQ = *(const bf16x8*)(Qt + (i * 16 + l15) * 128 + q * 8);
#pragma unroll
            for (int j = 0; j < 4; j++) {
                const bf16x8 bV = *(const bf16x8*)(Vt + (j * 16 + l15) * 128 + q * 8);
                const bf16x8 bQ = *(const bf16x8*)(Qt + (j * 16 + l15) * 128 + q * 8);
                aKV[j] = __builtin_amdgcn_mfma_f32_16x16x32_bf16(aK, bV, aKV[j], 0, 0, 0);
                aQV[j] = __builtin_amdgcn_mfma_f32_16x16x32_bf16(aQ, bV, aQV[j], 0, 0, 0);
                aQQ[j] = __builtin_amdgcn_mfma_f32_16x16x32_bf16(aQ, bQ, aQQ[j], 0, 0, 0);
            }
        }
    }

    float* Pb = P + ((size_t)bh * 8 + cn) * 12288;
#pragma unroll
    for (int j = 0; j < 4; j++)
#pragma unroll
        for (int r = 0; r < 4; r++) {
            const int row = i * 16 + quad * 4 + r, col = j * 16 + l15;
            Pb[row * 64 + col]        = aKV[j][r];
            Pb[4096 + row * 64 + col] = aQV[j][r];
            Pb[8192 + row * 64 + col] = aQQ[j][r];
        }
}

// Sum the 8 slabs per head
__global__ __launch_bounds__(256) void gram_reduce(const float* __restrict__ P,
                                                   float* __restrict__ M) {
    const int o = blockIdx.x * 256 + threadIdx.x;
    const int head = o / 12288, e = o % 12288;
    const float* Pb = P + (size_t)head * 8 * 12288 + e;
    float s = 0.f;
#pragma unroll
    for (int k = 0; k < 8; k++) s += Pb[(size_t)k * 12288];
    M[o] = s;
}

// ---------------------------------------------------------------------------
// W = 0.1*s*Mqv - 0.1*s^2 * (Mqq @ Mkv); emit TRANSPOSED bf16 Wt[d][k].
// ---------------------------------------------------------------------------
__global__ __launch_bounds__(256) void combine_w(const float* __restrict__ M,
                                                 HBF* __restrict__ Wt) {
    const int bh = blockIdx.x;
    const int by = blockIdx.y;
    const int t = threadIdx.x;
    __shared__ float Kv[4096];
    __shared__ float Qq8[512];
    const float* Mb = M + (size_t)bh * 12288;
#pragma unroll
    for (int r = 0; r < 16; r++) Kv[t + 256 * r] = Mb[t + 256 * r];
#pragma unroll
    for (int r = 0; r < 2; r++)  Qq8[t + 256 * r] = Mb[8192 + by * 512 + t + 256 * r];
    __syncthreads();

    const int il = t >> 5;
    const int j0 = (t & 31) * 2;
    float s0 = 0.f, s1 = 0.f;
#pragma unroll
    for (int k = 0; k < 64; k++) {
        const float q = Qq8[il * 64 + k];
        const float2 kv = *(const float2*)&Kv[k * 64 + j0];
        s0 += q * kv.x;
        s1 += q * kv.y;
    }
    const int i = by * 8 + il;
    const float w0 = STEP_C * (SCALE_C * Mb[4096 + i * 64 + j0]     - SCALE_C * SCALE_C * s0);
    const float w1 = STEP_C * (SCALE_C * Mb[4096 + i * 64 + j0 + 1] - SCALE_C * SCALE_C * s1);
    Wt[(size_t)bh * 4096 + j0 * 64 + i]       = __float2bfloat16(w0);
    Wt[(size_t)bh * 4096 + (j0 + 1) * 64 + i] = __float2bfloat16(w1);
}

// ---------------------------------------------------------------------------
// MFMA epilogue: AO[b,n,h*64+d] = relu(V + (Kn @ W)[n][d] - 0.05), bf16.
// ---------------------------------------------------------------------------
__global__ __launch_bounds__(256) void epilogue_attn(const HBF* __restrict__ Kn,
                                                     const HBF* __restrict__ Vb,
                                                     const HBF* __restrict__ Wt,
                                                     HBF* __restrict__ AO) {
    __shared__ char smem[34816];
    HBF* Ks  = (HBF*)smem;
    HBF* Wts = Ks + 128 * 64;
    float* Ps = (float*)smem;

    const int bh = blockIdx.x, cn = blockIdx.y;
    const int b = bh / 12, h = bh % 12;
    const int t = threadIdx.x, wv = t >> 6, lane = t & 63;
    const int l15 = lane & 15, quad = lane >> 4;
    const size_t kbase = ((size_t)bh * 2048 + cn * 128) * 64;
    const int srow = lane >> 3;
    const int schunk = (lane & 7) ^ srow;
    const int sub = t & 7;

#pragma unroll
    for (int rg = 0; rg < 4; rg++) {
        const int region = rg * 4 + wv;
        const int row = region * 8 + srow;
        __builtin_amdgcn_global_load_lds((const void*)(Kn + kbase + (size_t)row * 64 + schunk * 8),
                                         (void*)(Ks + region * 512), 16, 0, 0);
    }
#pragma unroll
    for (int rg = 0; rg < 2; rg++) {
        const int region = rg * 4 + wv;
        const int row = region * 8 + srow;
        __builtin_amdgcn_global_load_lds((const void*)(Wt + (size_t)bh * 4096 + (size_t)row * 64 + schunk * 8),
                                         (void*)(Wts + region * 512), 16, 0, 0);
    }
    __syncthreads();

    f32x4 acc[2][4] = {};
#pragma unroll
    for (int s = 0; s < 2; s++) {
        const int ch = (s * 4 + quad) ^ (l15 & 7);
        bf16x8 af[2], bfr[4];
#pragma unroll
        for (int i = 0; i < 2; i++) {
            const int row = wv * 32 + i * 16 + l15;
            af[i] = *reinterpret_cast<const bf16x8*>(&Ks[row * 64 + ch * 8]);
        }
#pragma unroll
        for (int j = 0; j < 4; j++) {
            const int d = j * 16 + l15;
            bfr[j] = *reinterpret_cast<const bf16x8*>(&Wts[d * 64 + ch * 8]);
        }
#pragma unroll
        for (int i = 0; i < 2; i++)
#pragma unroll
            for (int j = 0; j < 4; j++)
                acc[i][j] = __builtin_amdgcn_mfma_f32_16x16x32_bf16(af[i], bfr[j], acc[i][j], 0, 0, 0);
    }
    __syncthreads();

    float* Pw = Ps + wv * (32 * 68);
#pragma unroll
    for (int i = 0; i < 2; i++)
#pragma unroll
        for (int j = 0; j < 4; j++)
#pragma unroll
            for (int r = 0; r < 4; r++)
                Pw[(i * 16 + quad * 4 + r) * 68 + j * 16 + l15] = acc[i][j][r];
    __syncthreads();

#pragma unroll
    for (int rr = 0; rr < 4; rr++) {
        const int row = rr * 32 + (t >> 3);
        const float* prow = Ps + (row >> 5) * (32 * 68) + (row & 31) * 68 + sub * 8;
        const float4 p0 = *(const float4*)prow;
        const float4 p1 = *(const float4*)(prow + 4);
        uint4 rv = *(const uint4*)(Vb + kbase + (size_t)row * 64 + sub * 8);
        const HBF* hv = (const HBF*)&rv;
        const float pv[8] = {p0.x, p0.y, p0.z, p0.w, p1.x, p1.y, p1.z, p1.w};
        HBF o[8];
#pragma unroll
        for (int i = 0; i < 8; i++)
            o[i] = __float2bfloat16(fmaxf(__bfloat162float(hv[i]) + pv[i] - (STEP_C * LAMBD_C), 0.f));
        const int n = cn * 128 + row;
        *(uint4*)(AO + ((size_t)b * 2048 + n) * 768 + h * 64 + sub * 8) = *(const uint4*)o;
    }
}

// ---------------------------------------------------------------------------
extern "C" void kernel_launch(void* const* d_in, const int* in_sizes, int n_in,
                              void* d_out, int out_size, void* d_ws, size_t ws_size,
                              hipStream_t stream) {
    char* ws = (char*)d_ws;
    size_t off = 0;
    int*   flag   = (int*)(ws + off);   off += 16;
    HBF*   xb     = (HBF*)(ws + off);   off += (size_t)4096 * 768 * 2;
    HBF*   Wqkvb  = (HBF*)(ws + off);   off += (size_t)2304 * 768 * 2;
    HBF*   Wprojb = (HBF*)(ws + off);   off += (size_t)768 * 768 * 2;
    HBF*   bprojb = (HBF*)(ws + off);   off += 2048;
    HBF*   Kn     = (HBF*)(ws + off);   off += (size_t)24 * 2048 * 64 * 2;
    HBF*   Vb     = (HBF*)(ws + off);   off += (size_t)24 * 2048 * 64 * 2;
    HBF*   QKVt   = (HBF*)(ws + off);   off += (size_t)3 * 24 * 64 * 2048 * 2;
    float* P      = (float*)(ws + off); off += (size_t)24 * 8 * 12288 * 4;
    float* M      = (float*)(ws + off); off += (size_t)24 * 12288 * 4;
    HBF*   Wt     = (HBF*)(ws + off);   off += (size_t)24 * 4096 * 2;
    HBF*   AO     = (HBF*)(ws + off);   off += (size_t)4096 * 768 * 2;
    // total ~60 MB

    // 0) dtype detect (+ convert only if fp32 inputs)
    convert_all<<<512, 256, 0, stream>>>(d_in[0], d_in[1], d_in[2], d_in[3],
                                         xb, Wqkvb, Wprojb, bprojb, flag);

    // 1) qkv GEMM (double-buffered, 64x128 tiles, 1152 blocks):
    //    fused L2-norm + head-split natural (Kn, V) + transposed (QKVt)
    gemm_db<64, 128, false, false, true><<<dim3(64, 18), 256, 0, stream>>>(
        xb, d_in[0], Wqkvb, d_in[1], nullptr, nullptr,
        nullptr, Kn, Vb, QKVt, 4096, 2304, 768, flag);

    // 2) MFMA Gram partials (8 slabs) + tree reduce
    gram_mfma<<<dim3(24, 8), 256, 0, stream>>>(QKVt, P);
    gram_reduce<<<1152, 256, 0, stream>>>(P, M);

    // 3) W combine -> transposed bf16 Wt
    combine_w<<<dim3(24, 8), 256, 0, stream>>>(M, Wt);

    // 4) MFMA epilogue: relu(V + Kn@W - 0.05) -> [B,N,C] bf16
    epilogue_attn<<<dim3(24, 16), 256, 0, stream>>>(Kn, Vb, Wt, AO);

    // 5) out = AO @ Wproj^T + bproj (double-buffered, 64x64 tiles, 768 blocks)
    gemm_db<64, 64, true, true, false><<<dim3(64, 12), 256, 0, stream>>>(
        AO, AO, Wprojb, d_in[2], bprojb, d_in[3],
        d_out, nullptr, nullptr, nullptr, 4096, 768, 768, flag);
}